// Round 2
// baseline (7717.398 us; speedup 1.0000x reference)
//
#include <hip/hip_runtime.h>
#include <hip/hip_bf16.h>
#include <stdint.h>

#define SEQ     512
#define BATCH   32
#define TOKENS  16384   // BATCH*SEQ
#define EMB     1024
#define HEADS   16
#define DEPTH   4
#define K1      1536    // 3*F
#define H3      3072
#define MLPD    4096
#define CH      4096    // tokens per processing chunk
#define NCH     (TOKENS / CH)
#define CB      (CH / SEQ)   // batches per chunk = 8

typedef unsigned short u16;
typedef __attribute__((ext_vector_type(4))) float  f32x4;
typedef __attribute__((ext_vector_type(8))) short  s16x8;
typedef __attribute__((ext_vector_type(4))) u16    u16x4;

#define MFMA_16x16x32_BF16 __builtin_amdgcn_mfma_f32_16x16x32_bf16

__device__ __forceinline__ float bf2f(u16 u) {
  union { float f; uint32_t i; } c; c.i = ((uint32_t)u) << 16; return c.f;
}
__device__ __forceinline__ u16 f2bf(float f) {
  union { float f; uint32_t i; } c; c.f = f;
  uint32_t u = c.i;
  u += 0x7FFFu + ((u >> 16) & 1u);   // RNE
  return (u16)(u >> 16);
}
__device__ __forceinline__ void decomp(float x, u16& hi, u16& lo) {
  hi = f2bf(x);
  lo = f2bf(x - bf2f(hi));
}
__device__ __forceinline__ void gll16(const void* g, void* l) {
  __builtin_amdgcn_global_load_lds(
      (const __attribute__((address_space(1))) uint32_t*)g,
      (__attribute__((address_space(3))) uint32_t*)l, 16, 0, 0);
}

// ---------------------------------------------------------------------------
// Diagnostic fill (used only when ws_size is insufficient)
// ---------------------------------------------------------------------------
__global__ __launch_bounds__(256)
void fill_kernel(float* __restrict__ out, int n) {
  int i = blockIdx.x * 256 + threadIdx.x;
  if (i < n) out[i] = 1.0e6f;
}

// ---------------------------------------------------------------------------
// Weight transpose + bf16 hi/lo decompose:  W[K][N] f32  ->  Wt_hi/lo [N][K] bf16
// grid: (N/64, K/64), 256 threads
// ---------------------------------------------------------------------------
__global__ __launch_bounds__(256)
void wtrans_kernel(const float* __restrict__ W, u16* __restrict__ oHi,
                   u16* __restrict__ oLo, int K, int N) {
  const int n0 = blockIdx.x * 64, k0 = blockIdx.y * 64;
  __shared__ float tile[64][65];
  const int t = threadIdx.x;
  const int tr = t >> 4, tc4 = (t & 15) * 4;
#pragma unroll
  for (int rr = 0; rr < 4; ++rr) {
    int r = tr + rr * 16;
    const float4 v = *(const float4*)&W[(size_t)(k0 + r) * N + n0 + tc4];
    tile[r][tc4 + 0] = v.x; tile[r][tc4 + 1] = v.y;
    tile[r][tc4 + 2] = v.z; tile[r][tc4 + 3] = v.w;
  }
  __syncthreads();
#pragma unroll
  for (int rr = 0; rr < 4; ++rr) {
    int n = tr + rr * 16;
    u16x4 vh, vl;
#pragma unroll
    for (int j = 0; j < 4; ++j) {
      u16 hi, lo; decomp(tile[tc4 + j][n], hi, lo);
      vh[j] = hi; vl[j] = lo;
    }
    size_t o = (size_t)(n0 + n) * K + k0 + tc4;
    *(u16x4*)&oHi[o] = vh;
    *(u16x4*)&oLo[o] = vl;
  }
}

// ---------------------------------------------------------------------------
// Concat 3 feature streams + decompose, one CH-token chunk.
// Pointers are pre-offset to the chunk. fHi/fLo: [CH][1536] bf16.
// ---------------------------------------------------------------------------
__global__ __launch_bounds__(256)
void concat_kernel(const float* __restrict__ i1, const float* __restrict__ i2,
                   const float* __restrict__ tf, u16* __restrict__ fHi,
                   u16* __restrict__ fLo) {
  size_t gid = (size_t)blockIdx.x * 256 + threadIdx.x;
  size_t e = gid * 4;
  int m = (int)(e / K1), c = (int)(e % K1);
  const float* src = (c < 512) ? i1 : ((c < 1024) ? i2 : tf);
  const float4 v = *(const float4*)&src[(size_t)m * 512 + (c & 511)];
  u16x4 vh, vl;
  u16 hi, lo;
  decomp(v.x, hi, lo); vh[0] = hi; vl[0] = lo;
  decomp(v.y, hi, lo); vh[1] = hi; vl[1] = lo;
  decomp(v.z, hi, lo); vh[2] = hi; vl[2] = lo;
  decomp(v.w, hi, lo); vh[3] = hi; vl[3] = lo;
  size_t o = (size_t)m * K1 + c;
  *(u16x4*)&fHi[o] = vh;
  *(u16x4*)&fLo[o] = vl;
}

// ---------------------------------------------------------------------------
// sincos positional embedding table [512][1024] f32
// ---------------------------------------------------------------------------
__global__ __launch_bounds__(256)
void pos_kernel(float* __restrict__ pos) {
  const int t = blockIdx.x;
#pragma unroll
  for (int p = 0; p < 2; ++p) {
    int d = threadIdx.x + p * 256;              // 0..511
    double omega = pow(10000.0, -(double)d / 512.0);
    double v = (double)t * omega;
    pos[(size_t)t * EMB + d]       = (float)sin(v);
    pos[(size_t)t * EMB + 512 + d] = (float)cos(v);
  }
}

// ---------------------------------------------------------------------------
// LayerNorm over 1024; one wave per row. OUTF=0: bf16 hi/lo out, 1: f32 out.
// ---------------------------------------------------------------------------
template <int OUTF>
__global__ __launch_bounds__(256)
void ln_kernel(const float* __restrict__ x, const float* __restrict__ scale,
               const float* __restrict__ bias, u16* __restrict__ hHi,
               u16* __restrict__ hLo, float* __restrict__ outF) {
  const int w = threadIdx.x >> 6, lane = threadIdx.x & 63;
  const int row = blockIdx.x * 4 + w;
  const float* xr = x + (size_t)row * EMB;
  float4 vv[4];
  float s = 0.f, s2 = 0.f;
#pragma unroll
  for (int j = 0; j < 4; ++j) {
    vv[j] = *(const float4*)&xr[j * 256 + lane * 4];
    s  += vv[j].x + vv[j].y + vv[j].z + vv[j].w;
    s2 += vv[j].x * vv[j].x + vv[j].y * vv[j].y + vv[j].z * vv[j].z + vv[j].w * vv[j].w;
  }
#pragma unroll
  for (int m = 1; m < 64; m <<= 1) {
    s  += __shfl_xor(s, m);
    s2 += __shfl_xor(s2, m);
  }
  const float mu = s * (1.f / EMB);
  const float var = s2 * (1.f / EMB) - mu * mu;
  const float rs = rsqrtf(var + 1e-6f);
#pragma unroll
  for (int j = 0; j < 4; ++j) {
    int c = j * 256 + lane * 4;
    const float4 sc = *(const float4*)&scale[c];
    const float4 bi = *(const float4*)&bias[c];
    float h0 = (vv[j].x - mu) * rs * sc.x + bi.x;
    float h1 = (vv[j].y - mu) * rs * sc.y + bi.y;
    float h2 = (vv[j].z - mu) * rs * sc.z + bi.z;
    float h3 = (vv[j].w - mu) * rs * sc.w + bi.w;
    size_t o = (size_t)row * EMB + c;
    if (OUTF) {
      *(float4*)&outF[o] = make_float4(h0, h1, h2, h3);
    } else {
      u16x4 vh, vl; u16 hi, lo;
      decomp(h0, hi, lo); vh[0] = hi; vl[0] = lo;
      decomp(h1, hi, lo); vh[1] = hi; vl[1] = lo;
      decomp(h2, hi, lo); vh[2] = hi; vl[2] = lo;
      decomp(h3, hi, lo); vh[3] = hi; vl[3] = lo;
      *(u16x4*)&hHi[o] = vh;
      *(u16x4*)&hLo[o] = vl;
    }
  }
}

// ---------------------------------------------------------------------------
// bf16x3 split GEMM: C = (Ahi+Alo) @ (Bhi+Blo)^T  with fp32 MFMA accumulate.
// A: [M][K] bf16 hi/lo; B: [N][K] bf16 hi/lo (pre-transposed weights).
// 128x128 tile, BK=32, 4 waves (2x2), 4x4 fragments. m97 structure.
// EPI: 0 = +bias +pos -> f32   (MLP-in)
//      1 = +bias -> bf16 hi    (QKV)
//      2 = +bias +res -> f32   (proj residual)
//      3 = gelu -> bf16 hi/lo  (fc1)
//      4 = +res -> f32         (fc2 residual)
// ---------------------------------------------------------------------------
template <int EPI>
__global__ __launch_bounds__(256, 2)
void gemm3_kernel(const u16* __restrict__ Ahi, const u16* __restrict__ Alo,
                  const u16* __restrict__ Bhi, const u16* __restrict__ Blo,
                  int K, int N, const float* __restrict__ bias,
                  const float* __restrict__ extra, float* __restrict__ outF,
                  u16* __restrict__ outHi, u16* __restrict__ outLo) {
  const int tid = threadIdx.x;
  const int lane = tid & 63;
  const int w = tid >> 6;
  const int wm = w >> 1, wn = w & 1;
  const int bm = blockIdx.x * 128, bn = blockIdx.y * 128;
  const int l15 = lane & 15, g4 = lane >> 4;

  __shared__ u16 lds[16384];  // Ahi[0] Alo[4096] Bhi[8192] Blo[12288], u16 idx

  f32x4 acc[4][4];
#pragma unroll
  for (int i = 0; i < 4; ++i)
#pragma unroll
    for (int j = 0; j < 4; ++j) acc[i][j] = f32x4{0.f, 0.f, 0.f, 0.f};

  for (int k0 = 0; k0 < K; k0 += 32) {
    // ---- stage 4 tiles via global_load_lds, source pre-swizzled (g ^= (r>>1)&3)
#pragma unroll
    for (int p = 0; p < 2; ++p) {
      int c = p * 256 + tid;
      int r = c >> 2;
      int gg = (c & 3) ^ ((r >> 1) & 3);
      size_t goffA = (size_t)(bm + r) * K + k0 + gg * 8;
      size_t goffB = (size_t)(bn + r) * K + k0 + gg * 8;
      gll16(Ahi + goffA, &lds[0     + c * 8]);
      gll16(Alo + goffA, &lds[4096  + c * 8]);
      gll16(Bhi + goffB, &lds[8192  + c * 8]);
      gll16(Blo + goffB, &lds[12288 + c * 8]);
    }
    __syncthreads();
    s16x8 ah[4], al[4], bh[4], bl[4];
#pragma unroll
    for (int mi = 0; mi < 4; ++mi) {
      int r = wm * 64 + mi * 16 + l15;
      int chunk = (r << 2) | (g4 ^ ((r >> 1) & 3));
      ah[mi] = *(const s16x8*)&lds[0    + chunk * 8];
      al[mi] = *(const s16x8*)&lds[4096 + chunk * 8];
    }
#pragma unroll
    for (int ni = 0; ni < 4; ++ni) {
      int r = wn * 64 + ni * 16 + l15;
      int chunk = (r << 2) | (g4 ^ ((r >> 1) & 3));
      bh[ni] = *(const s16x8*)&lds[8192  + chunk * 8];
      bl[ni] = *(const s16x8*)&lds[12288 + chunk * 8];
    }
#pragma unroll
    for (int mi = 0; mi < 4; ++mi)
#pragma unroll
      for (int ni = 0; ni < 4; ++ni) {
        acc[mi][ni] = MFMA_16x16x32_BF16(ah[mi], bh[ni], acc[mi][ni], 0, 0, 0);
        acc[mi][ni] = MFMA_16x16x32_BF16(ah[mi], bl[ni], acc[mi][ni], 0, 0, 0);
        acc[mi][ni] = MFMA_16x16x32_BF16(al[mi], bh[ni], acc[mi][ni], 0, 0, 0);
      }
    __syncthreads();
  }
  // ---- epilogue: C/D layout row=(lane>>4)*4+reg, col=lane&15 (m89-verified)
#pragma unroll
  for (int mi = 0; mi < 4; ++mi) {
#pragma unroll
    for (int ni = 0; ni < 4; ++ni) {
      int gc = bn + wn * 64 + ni * 16 + l15;
      float bv = (EPI == 0 || EPI == 1 || EPI == 2) ? bias[gc] : 0.f;
#pragma unroll
      for (int r_ = 0; r_ < 4; ++r_) {
        int gr = bm + wm * 64 + mi * 16 + g4 * 4 + r_;
        float v = acc[mi][ni][r_] + bv;
        size_t o = (size_t)gr * N + gc;
        if (EPI == 0) {
          outF[o] = v + extra[(size_t)(gr & (SEQ - 1)) * EMB + gc];
        } else if (EPI == 1) {
          outHi[o] = f2bf(v);
        } else if (EPI == 2 || EPI == 4) {
          outF[o] = v + extra[o];
        } else {  // EPI == 3: tanh-approx GELU -> bf16 hi/lo
          float t3 = v + 0.044715f * v * v * v;
          float gl = 0.5f * v * (1.f + tanhf(0.7978845608028654f * t3));
          u16 hi, lo; decomp(gl, hi, lo);
          outHi[o] = hi; outLo[o] = lo;
        }
      }
    }
  }
}

// ---------------------------------------------------------------------------
// Flash attention fwd, one CH-token chunk (CB batches). grid (SEQ/64, HEADS, CB),
// 256 thr = 4 waves, each wave owns 16 q-rows. qkv: bf16 [CH][3072] (q|k|v).
// bf16 MFMA, f32 online softmax. Outputs o decomposed to hi/lo bf16 (local rows).
// ---------------------------------------------------------------------------
__global__ __launch_bounds__(256, 2)
void attn_kernel(const u16* __restrict__ qkv, u16* __restrict__ oHi,
                 u16* __restrict__ oLo) {
  const int qb = blockIdx.x, h = blockIdx.y, b = blockIdx.z;
  const int tid = threadIdx.x, lane = tid & 63, w = tid >> 6;
  const int l15 = lane & 15, g4 = lane >> 4;

  __shared__ u16 smem[2048 + 2560 + 2048];
  u16* Klds = smem;                       // [32][64] XOR-swizzled (^ (key&7) granules)
  u16* VT   = smem + 2048;                // [64][40] transposed V, padded
  u16* Pw   = smem + 2048 + 2560 + w * 512;  // per-wave P [16][32], chunk-swizzled

  const int q0 = qb * 64 + w * 16;
  const size_t base = (size_t)b * SEQ * H3 + (size_t)h * 64;

  s16x8 qf0, qf1;
  {
    const u16* qp = qkv + base + (size_t)(q0 + l15) * H3 + g4 * 8;
    qf0 = *(const s16x8*)qp;
    qf1 = *(const s16x8*)(qp + 32);
  }

  f32x4 of[4];
#pragma unroll
  for (int n = 0; n < 4; ++n) of[n] = f32x4{0.f, 0.f, 0.f, 0.f};
  float mrow[4] = {-1e30f, -1e30f, -1e30f, -1e30f};
  float lrow[4] = {0.f, 0.f, 0.f, 0.f};

  for (int kt = 0; kt < SEQ; kt += 32) {
    {  // stage K tile (global_load_lds, source pre-swizzled)
      int r = tid >> 3;
      int jj = (tid & 7) ^ (r & 7);
      gll16(qkv + base + (size_t)(kt + r) * H3 + EMB + jj * 8, &Klds[tid * 8]);
    }
    {  // stage V transposed: VT[d][key]
      int key = tid >> 3, j = tid & 7;
      s16x8 v = *(const s16x8*)(qkv + base + (size_t)(kt + key) * H3 + 2 * EMB + j * 8);
#pragma unroll
      for (int i = 0; i < 8; ++i) VT[(j * 8 + i) * 40 + key] = (u16)v[i];
    }
    __syncthreads();
    // ---- QK^T: S[16q][32k] in two 16-key fragments
    const int key0 = l15, key1 = 16 + l15;
    s16x8 kf00 = *(const s16x8*)&Klds[key0 * 64 + (((0 + g4) ^ (key0 & 7)) * 8)];
    s16x8 kf01 = *(const s16x8*)&Klds[key0 * 64 + (((4 + g4) ^ (key0 & 7)) * 8)];
    s16x8 kf10 = *(const s16x8*)&Klds[key1 * 64 + (((0 + g4) ^ (key1 & 7)) * 8)];
    s16x8 kf11 = *(const s16x8*)&Klds[key1 * 64 + (((4 + g4) ^ (key1 & 7)) * 8)];
    f32x4 z = f32x4{0.f, 0.f, 0.f, 0.f};
    f32x4 s0 = MFMA_16x16x32_BF16(qf0, kf00, z, 0, 0, 0);
    s0 = MFMA_16x16x32_BF16(qf1, kf01, s0, 0, 0, 0);
    f32x4 s1 = MFMA_16x16x32_BF16(qf0, kf10, z, 0, 0, 0);
    s1 = MFMA_16x16x32_BF16(qf1, kf11, s1, 0, 0, 0);
    // ---- online softmax (scale 0.125 folded into exp arg)
#pragma unroll
    for (int r_ = 0; r_ < 4; ++r_) {
      float mx = fmaxf(s0[r_], s1[r_]);
      mx = fmaxf(mx, __shfl_xor(mx, 1));
      mx = fmaxf(mx, __shfl_xor(mx, 2));
      mx = fmaxf(mx, __shfl_xor(mx, 4));
      mx = fmaxf(mx, __shfl_xor(mx, 8));
      float mnew = fmaxf(mrow[r_], mx);
      float alpha = __expf((mrow[r_] - mnew) * 0.125f);
      mrow[r_] = mnew;
      float p0 = __expf((s0[r_] - mnew) * 0.125f);
      float p1 = __expf((s1[r_] - mnew) * 0.125f);
      float ts = p0 + p1;
      ts += __shfl_xor(ts, 1);
      ts += __shfl_xor(ts, 2);
      ts += __shfl_xor(ts, 4);
      ts += __shfl_xor(ts, 8);
      lrow[r_] = lrow[r_] * alpha + ts;
      of[0][r_] *= alpha; of[1][r_] *= alpha;
      of[2][r_] *= alpha; of[3][r_] *= alpha;
      int row = g4 * 4 + r_;
      int sw = (row >> 1) & 3;
      int c0 = (l15 >> 3) ^ sw;
      int c1 = (2 + (l15 >> 3)) ^ sw;
      Pw[(row * 4 + c0) * 8 + (l15 & 7)] = f2bf(p0);
      Pw[(row * 4 + c1) * 8 + (l15 & 7)] = f2bf(p1);
    }
    // ---- PV
    {
      int pchunk = (l15 << 2) | (g4 ^ ((l15 >> 1) & 3));
      s16x8 pf = *(const s16x8*)&Pw[pchunk * 8];
#pragma unroll
      for (int n = 0; n < 4; ++n) {
        s16x8 vf = *(const s16x8*)&VT[(n * 16 + l15) * 40 + g4 * 8];
        of[n] = MFMA_16x16x32_BF16(pf, vf, of[n], 0, 0, 0);
      }
    }
    __syncthreads();
  }
  // ---- epilogue: o = of / l, decompose to bf16 hi/lo
#pragma unroll
  for (int r_ = 0; r_ < 4; ++r_) {
    float inv = 1.f / lrow[r_];
    int qrow = q0 + g4 * 4 + r_;
    size_t ob = (size_t)(b * SEQ + qrow) * EMB + h * 64;
#pragma unroll
    for (int n = 0; n < 4; ++n) {
      u16 hi, lo; decomp(of[n][r_] * inv, hi, lo);
      oHi[ob + n * 16 + l15] = hi;
      oLo[ob + n * 16 + l15] = lo;
    }
  }
}

// ---------------------------------------------------------------------------
extern "C" void kernel_launch(void* const* d_in, const int* in_sizes, int n_in,
                              void* d_out, int out_size, void* d_ws, size_t ws_size,
                              hipStream_t stream) {
  const float* image1     = (const float*)d_in[0];
  const float* image2     = (const float*)d_in[1];
  const float* text_feat  = (const float*)d_in[2];
  const float* mlp_kernel = (const float*)d_in[3];
  const float* mlp_bias   = (const float*)d_in[4];
  const float* ln1_scale  = (const float*)d_in[5];
  const float* ln1_bias   = (const float*)d_in[6];
  const float* qkv_kernel = (const float*)d_in[7];
  const float* qkv_bias   = (const float*)d_in[8];
  const float* proj_kernel= (const float*)d_in[9];
  const float* proj_bias  = (const float*)d_in[10];
  const float* ln2_scale  = (const float*)d_in[11];
  const float* ln2_bias   = (const float*)d_in[12];
  const float* fc1_kernel = (const float*)d_in[13];
  const float* fc2_kernel = (const float*)d_in[14];
  const float* lnf_scale  = (const float*)d_in[15];
  const float* lnf_bias   = (const float*)d_in[16];

  // ---- workspace layout (bytes), ~194 MB total
  size_t off = 0;
  auto take = [&](size_t bytes) { size_t o = off; off += (bytes + 255) & ~(size_t)255; return o; };
  char* ws = (char*)d_ws;
  const size_t oX    = take((size_t)TOKENS * EMB * 4);       // 64 MB residual (f32)
  const size_t oPos  = take((size_t)SEQ * EMB * 4);          //  2 MB
  const size_t oHHi  = take((size_t)CH * EMB * 2);           //  8 MB
  const size_t oHLo  = take((size_t)CH * EMB * 2);           //  8 MB
  const size_t oOHi  = take((size_t)CH * EMB * 2);           //  8 MB
  const size_t oOLo  = take((size_t)CH * EMB * 2);           //  8 MB
  const size_t oBig  = take((size_t)CH * MLPD * 2 * 2);      // 64 MB (feats | qkv | m hi/lo)
  const size_t oWbuf = take((size_t)4 * 8 * 1024 * 1024);    // 32 MB (4 x 8MB weight slots)
  if (off > ws_size) {  // diagnostic: absmax ~1e6 next round => ws too small
    fill_kernel<<<(out_size + 255) / 256, 256, 0, stream>>>((float*)d_out, out_size);
    return;
  }

  float* x   = (float*)(ws + oX);
  float* pos = (float*)(ws + oPos);
  u16* hHi   = (u16*)(ws + oHHi);
  u16* hLo   = (u16*)(ws + oHLo);
  u16* oHi   = (u16*)(ws + oOHi);
  u16* oLo   = (u16*)(ws + oOLo);
  u16* big   = (u16*)(ws + oBig);
  u16* s0    = (u16*)(ws + oWbuf);
  u16* s1    = s0 + (size_t)4 * 1024 * 1024;   // 8MB slots in u16 units
  u16* s2    = s1 + (size_t)4 * 1024 * 1024;
  u16* s3    = s2 + (size_t)4 * 1024 * 1024;

  pos_kernel<<<SEQ, 256, 0, stream>>>(pos);

  // ---- MLP-in: x = concat(feats) @ W1 + b + pos, chunked
  wtrans_kernel<<<dim3(EMB / 64, K1 / 64), 256, 0, stream>>>(mlp_kernel, s0, s1, K1, EMB);
  for (int c = 0; c < NCH; ++c) {
    const size_t fo = (size_t)c * CH * 512;
    u16* fHi = big;
    u16* fLo = big + (size_t)CH * K1;
    concat_kernel<<<CH * K1 / 1024, 256, 0, stream>>>(image1 + fo, image2 + fo, text_feat + fo, fHi, fLo);
    gemm3_kernel<0><<<dim3(CH / 128, EMB / 128), 256, 0, stream>>>(
        fHi, fLo, s0, s1, K1, EMB, mlp_bias, pos, x + (size_t)c * CH * EMB, nullptr, nullptr);
  }

  for (int i = 0; i < DEPTH; ++i) {
    // ---- attention phase: qkv weights -> s0/s1, proj -> s2/s3
    wtrans_kernel<<<dim3(H3 / 64, EMB / 64), 256, 0, stream>>>(
        qkv_kernel + (size_t)i * EMB * H3, s0, s1, EMB, H3);
    wtrans_kernel<<<dim3(EMB / 64, EMB / 64), 256, 0, stream>>>(
        proj_kernel + (size_t)i * EMB * EMB, s2, s3, EMB, EMB);
    for (int c = 0; c < NCH; ++c) {
      float* xc = x + (size_t)c * CH * EMB;
      ln_kernel<0><<<CH / 4, 256, 0, stream>>>(xc, ln1_scale + i * EMB, ln1_bias + i * EMB,
                                               hHi, hLo, nullptr);
      gemm3_kernel<1><<<dim3(CH / 128, H3 / 128), 256, 0, stream>>>(
          hHi, hLo, s0, s1, EMB, H3, qkv_bias + i * H3, nullptr, nullptr, big, nullptr);
      attn_kernel<<<dim3(SEQ / 64, HEADS, CB), 256, 0, stream>>>(big, oHi, oLo);
      gemm3_kernel<2><<<dim3(CH / 128, EMB / 128), 256, 0, stream>>>(
          oHi, oLo, s2, s3, EMB, EMB, proj_bias + i * EMB, xc, xc, nullptr, nullptr);
    }
    // ---- MLP phase: fc1 -> s0/s1, fc2 -> s2/s3
    wtrans_kernel<<<dim3(MLPD / 64, EMB / 64), 256, 0, stream>>>(
        fc1_kernel + (size_t)i * EMB * MLPD, s0, s1, EMB, MLPD);
    wtrans_kernel<<<dim3(EMB / 64, MLPD / 64), 256, 0, stream>>>(
        fc2_kernel + (size_t)i * MLPD * EMB, s2, s3, MLPD, EMB);
    for (int c = 0; c < NCH; ++c) {
      float* xc = x + (size_t)c * CH * EMB;
      u16* mHi = big;
      u16* mLo = big + (size_t)CH * MLPD;
      ln_kernel<0><<<CH / 4, 256, 0, stream>>>(xc, ln2_scale + i * EMB, ln2_bias + i * EMB,
                                               hHi, hLo, nullptr);
      gemm3_kernel<3><<<dim3(CH / 128, MLPD / 128), 256, 0, stream>>>(
          hHi, hLo, s0, s1, EMB, MLPD, nullptr, nullptr, nullptr, mHi, mLo);
      gemm3_kernel<4><<<dim3(CH / 128, EMB / 128), 256, 0, stream>>>(
          mHi, mLo, s2, s3, MLPD, EMB, nullptr, xc, xc, nullptr, nullptr);
    }
  }
  ln_kernel<1><<<TOKENS / 4, 256, 0, stream>>>(x, lnf_scale, lnf_bias,
                                               nullptr, nullptr, (float*)d_out);
}

// Round 5
// 4009.922 us; speedup vs baseline: 1.9246x; 1.9246x over previous
//
#include <hip/hip_runtime.h>
#include <hip/hip_bf16.h>
#include <stdint.h>

#define SEQ     512
#define BATCH   32
#define TOKENS  16384   // BATCH*SEQ
#define EMB     1024
#define HEADS   16
#define DEPTH   4
#define K1      1536    // 3*F
#define H3      3072
#define MLPD    4096
#define CH      4096    // tokens per processing chunk
#define NCH     (TOKENS / CH)
#define CB      (CH / SEQ)   // batches per chunk = 8

typedef unsigned short u16;
typedef __attribute__((ext_vector_type(4))) float  f32x4;
typedef __attribute__((ext_vector_type(8))) short  s16x8;
typedef __attribute__((ext_vector_type(4))) u16    u16x4;

#define MFMA_16x16x32_BF16 __builtin_amdgcn_mfma_f32_16x16x32_bf16

__device__ __forceinline__ u16 f2bf(float f) {
  union { float f; uint32_t i; } c; c.f = f;
  uint32_t u = c.i;
  u += 0x7FFFu + ((u >> 16) & 1u);   // RNE
  return (u16)(u >> 16);
}
__device__ __forceinline__ void gll16(const void* g, void* l) {
  __builtin_amdgcn_global_load_lds(
      (const __attribute__((address_space(1))) uint32_t*)g,
      (__attribute__((address_space(3))) uint32_t*)l, 16, 0, 0);
}

// ---------------------------------------------------------------------------
// Diagnostic fill (used only when ws_size is insufficient)
// ---------------------------------------------------------------------------
__global__ __launch_bounds__(256)
void fill_kernel(float* __restrict__ out, int n) {
  int i = blockIdx.x * 256 + threadIdx.x;
  if (i < n) out[i] = 1.0e6f;
}

// ---------------------------------------------------------------------------
// Weight transpose + bf16 round:  W[K][N] f32  ->  Wt [N][K] bf16
// grid: (N/64, K/64), 256 threads
// ---------------------------------------------------------------------------
__global__ __launch_bounds__(256)
void wtrans_kernel(const float* __restrict__ W, u16* __restrict__ oHi,
                   int K, int N) {
  const int n0 = blockIdx.x * 64, k0 = blockIdx.y * 64;
  __shared__ float tile[64][65];
  const int t = threadIdx.x;
  const int tr = t >> 4, tc4 = (t & 15) * 4;
#pragma unroll
  for (int rr = 0; rr < 4; ++rr) {
    int r = tr + rr * 16;
    const float4 v = *(const float4*)&W[(size_t)(k0 + r) * N + n0 + tc4];
    tile[r][tc4 + 0] = v.x; tile[r][tc4 + 1] = v.y;
    tile[r][tc4 + 2] = v.z; tile[r][tc4 + 3] = v.w;
  }
  __syncthreads();
#pragma unroll
  for (int rr = 0; rr < 4; ++rr) {
    int n = tr + rr * 16;
    u16x4 vh;
#pragma unroll
    for (int j = 0; j < 4; ++j) vh[j] = f2bf(tile[tc4 + j][n]);
    size_t o = (size_t)(n0 + n) * K + k0 + tc4;
    *(u16x4*)&oHi[o] = vh;
  }
}

// ---------------------------------------------------------------------------
// Concat 3 feature streams -> bf16 [CH][1536], one CH-token chunk.
// ---------------------------------------------------------------------------
__global__ __launch_bounds__(256)
void concat_kernel(const float* __restrict__ i1, const float* __restrict__ i2,
                   const float* __restrict__ tf, u16* __restrict__ fHi) {
  size_t gid = (size_t)blockIdx.x * 256 + threadIdx.x;
  size_t e = gid * 4;
  int m = (int)(e / K1), c = (int)(e % K1);
  const float* src = (c < 512) ? i1 : ((c < 1024) ? i2 : tf);
  const float4 v = *(const float4*)&src[(size_t)m * 512 + (c & 511)];
  u16x4 vh;
  vh[0] = f2bf(v.x); vh[1] = f2bf(v.y); vh[2] = f2bf(v.z); vh[3] = f2bf(v.w);
  *(u16x4*)&fHi[(size_t)m * K1 + c] = vh;
}

// ---------------------------------------------------------------------------
// sincos positional embedding table [512][1024] f32
// ---------------------------------------------------------------------------
__global__ __launch_bounds__(256)
void pos_kernel(float* __restrict__ pos) {
  const int t = blockIdx.x;
#pragma unroll
  for (int p = 0; p < 2; ++p) {
    int d = threadIdx.x + p * 256;              // 0..511
    double omega = pow(10000.0, -(double)d / 512.0);
    double v = (double)t * omega;
    pos[(size_t)t * EMB + d]       = (float)sin(v);
    pos[(size_t)t * EMB + 512 + d] = (float)cos(v);
  }
}

// ---------------------------------------------------------------------------
// LayerNorm over 1024; one wave per row. OUTF=0: bf16 out, 1: f32 out.
// ---------------------------------------------------------------------------
template <int OUTF>
__global__ __launch_bounds__(256)
void ln_kernel(const float* __restrict__ x, const float* __restrict__ scale,
               const float* __restrict__ bias, u16* __restrict__ hHi,
               float* __restrict__ outF) {
  const int w = threadIdx.x >> 6, lane = threadIdx.x & 63;
  const int row = blockIdx.x * 4 + w;
  const float* xr = x + (size_t)row * EMB;
  float4 vv[4];
  float s = 0.f, s2 = 0.f;
#pragma unroll
  for (int j = 0; j < 4; ++j) {
    vv[j] = *(const float4*)&xr[j * 256 + lane * 4];
    s  += vv[j].x + vv[j].y + vv[j].z + vv[j].w;
    s2 += vv[j].x * vv[j].x + vv[j].y * vv[j].y + vv[j].z * vv[j].z + vv[j].w * vv[j].w;
  }
#pragma unroll
  for (int m = 1; m < 64; m <<= 1) {
    s  += __shfl_xor(s, m);
    s2 += __shfl_xor(s2, m);
  }
  const float mu = s * (1.f / EMB);
  const float var = s2 * (1.f / EMB) - mu * mu;
  const float rs = rsqrtf(var + 1e-6f);
#pragma unroll
  for (int j = 0; j < 4; ++j) {
    int c = j * 256 + lane * 4;
    const float4 sc = *(const float4*)&scale[c];
    const float4 bi = *(const float4*)&bias[c];
    float h0 = (vv[j].x - mu) * rs * sc.x + bi.x;
    float h1 = (vv[j].y - mu) * rs * sc.y + bi.y;
    float h2 = (vv[j].z - mu) * rs * sc.z + bi.z;
    float h3 = (vv[j].w - mu) * rs * sc.w + bi.w;
    size_t o = (size_t)row * EMB + c;
    if (OUTF) {
      *(float4*)&outF[o] = make_float4(h0, h1, h2, h3);
    } else {
      u16x4 vh;
      vh[0] = f2bf(h0); vh[1] = f2bf(h1); vh[2] = f2bf(h2); vh[3] = f2bf(h3);
      *(u16x4*)&hHi[o] = vh;
    }
  }
}

// ---------------------------------------------------------------------------
// Single-pass bf16 GEMM: C = A @ B^T, fp32 MFMA accumulate.
// A: [M][K] bf16; B: [N][K] bf16 (pre-transposed weights).
// 128x128 tile, BK=32, 4 waves (2x2), 4x4 fragments, 2-phase double-buffered
// LDS (stage k+1 in flight during MFMA of k; one barrier per K-step).
// EPI: 0 = +bias +pos -> f32   (MLP-in)
//      1 = +bias -> bf16       (QKV)
//      2 = +bias +res -> f32   (proj residual)
//      3 = gelu -> bf16        (fc1)
//      4 = +res -> f32         (fc2 residual)
// ---------------------------------------------------------------------------
template <int EPI>
__global__ __launch_bounds__(256, 3)
void gemm1_kernel(const u16* __restrict__ A, const u16* __restrict__ B,
                  int K, int N, const float* __restrict__ bias,
                  const float* __restrict__ extra, float* __restrict__ outF,
                  u16* __restrict__ outHi) {
  const int tid = threadIdx.x;
  const int lane = tid & 63;
  const int w = tid >> 6;
  const int wm = w >> 1, wn = w & 1;
  const int bm = blockIdx.x * 128, bn = blockIdx.y * 128;
  const int l15 = lane & 15, g4 = lane >> 4;

  // [buf][ A 4096 u16 | B 4096 u16 ]  x2 buffers = 32 KB
  __shared__ u16 lds[16384];

  f32x4 acc[4][4];
#pragma unroll
  for (int i = 0; i < 4; ++i)
#pragma unroll
    for (int j = 0; j < 4; ++j) acc[i][j] = f32x4{0.f, 0.f, 0.f, 0.f};

  // stage one 128x32 A-tile + B-tile into buffer `buf` (source pre-swizzled
  // by granule: gg = g ^ ((r>>1)&3), matching the swizzled ds_read below)
  auto stage = [&](int buf, int k0) {
#pragma unroll
    for (int p = 0; p < 2; ++p) {
      int c = p * 256 + tid;              // chunk 0..511
      int r = c >> 2;
      int gg = (c & 3) ^ ((r >> 1) & 3);
      gll16(A + (size_t)(bm + r) * K + k0 + gg * 8, &lds[buf * 8192 + c * 8]);
      gll16(B + (size_t)(bn + r) * K + k0 + gg * 8, &lds[buf * 8192 + 4096 + c * 8]);
    }
  };

  const int nk = K >> 5;
  stage(0, 0);
  for (int kt = 0; kt < nk; ++kt) {
    const int cur = kt & 1;
    __syncthreads();                       // drains own vmcnt, syncs waves
    if (kt + 1 < nk) stage(cur ^ 1, (kt + 1) * 32);
    s16x8 ah[4], bh[4];
#pragma unroll
    for (int mi = 0; mi < 4; ++mi) {
      int r = wm * 64 + mi * 16 + l15;
      int chunk = (r << 2) | (g4 ^ ((r >> 1) & 3));
      ah[mi] = *(const s16x8*)&lds[cur * 8192 + chunk * 8];
    }
#pragma unroll
    for (int ni = 0; ni < 4; ++ni) {
      int r = wn * 64 + ni * 16 + l15;
      int chunk = (r << 2) | (g4 ^ ((r >> 1) & 3));
      bh[ni] = *(const s16x8*)&lds[cur * 8192 + 4096 + chunk * 8];
    }
#pragma unroll
    for (int mi = 0; mi < 4; ++mi)
#pragma unroll
      for (int ni = 0; ni < 4; ++ni)
        acc[mi][ni] = MFMA_16x16x32_BF16(ah[mi], bh[ni], acc[mi][ni], 0, 0, 0);
  }
  // ---- epilogue: C/D layout row=(lane>>4)*4+reg, col=lane&15 (m89-verified)
#pragma unroll
  for (int mi = 0; mi < 4; ++mi) {
#pragma unroll
    for (int ni = 0; ni < 4; ++ni) {
      int gc = bn + wn * 64 + ni * 16 + l15;
      float bv = (EPI == 0 || EPI == 1 || EPI == 2) ? bias[gc] : 0.f;
#pragma unroll
      for (int r_ = 0; r_ < 4; ++r_) {
        int gr = bm + wm * 64 + mi * 16 + g4 * 4 + r_;
        float v = acc[mi][ni][r_] + bv;
        size_t o = (size_t)gr * N + gc;
        if (EPI == 0) {
          outF[o] = v + extra[(size_t)(gr & (SEQ - 1)) * EMB + gc];
        } else if (EPI == 1) {
          outHi[o] = f2bf(v);
        } else if (EPI == 2 || EPI == 4) {
          outF[o] = v + extra[o];
        } else {  // EPI == 3: tanh-approx GELU -> bf16
          float t3 = v + 0.044715f * v * v * v;
          float gl = 0.5f * v * (1.f + tanhf(0.7978845608028654f * t3));
          outHi[o] = f2bf(gl);
        }
      }
    }
  }
}

// ---------------------------------------------------------------------------
// Flash attention fwd, one CH-token chunk (CB batches). grid (SEQ/64, HEADS, CB),
// 256 thr = 4 waves, each wave owns 16 q-rows. qkv: bf16 [CH][3072] (q|k|v).
// bf16 MFMA, f32 online softmax. Output o as bf16.
// ---------------------------------------------------------------------------
__global__ __launch_bounds__(256, 2)
void attn_kernel(const u16* __restrict__ qkv, u16* __restrict__ oHi) {
  const int qb = blockIdx.x, h = blockIdx.y, b = blockIdx.z;
  const int tid = threadIdx.x, lane = tid & 63, w = tid >> 6;
  const int l15 = lane & 15, g4 = lane >> 4;

  __shared__ u16 smem[2048 + 2560 + 2048];
  u16* Klds = smem;                       // [32][64] XOR-swizzled (^ (key&7) granules)
  u16* VT   = smem + 2048;                // [64][40] transposed V, padded
  u16* Pw   = smem + 2048 + 2560 + w * 512;  // per-wave P [16][32], chunk-swizzled

  const int q0 = qb * 64 + w * 16;
  const size_t base = (size_t)b * SEQ * H3 + (size_t)h * 64;

  s16x8 qf0, qf1;
  {
    const u16* qp = qkv + base + (size_t)(q0 + l15) * H3 + g4 * 8;
    qf0 = *(const s16x8*)qp;
    qf1 = *(const s16x8*)(qp + 32);
  }

  f32x4 of[4];
#pragma unroll
  for (int n = 0; n < 4; ++n) of[n] = f32x4{0.f, 0.f, 0.f, 0.f};
  float mrow[4] = {-1e30f, -1e30f, -1e30f, -1e30f};
  float lrow[4] = {0.f, 0.f, 0.f, 0.f};

  for (int kt = 0; kt < SEQ; kt += 32) {
    {  // stage K tile (global_load_lds, source pre-swizzled)
      int r = tid >> 3;
      int jj = (tid & 7) ^ (r & 7);
      gll16(qkv + base + (size_t)(kt + r) * H3 + EMB + jj * 8, &Klds[tid * 8]);
    }
    {  // stage V transposed: VT[d][key]
      int key = tid >> 3, j = tid & 7;
      s16x8 v = *(const s16x8*)(qkv + base + (size_t)(kt + key) * H3 + 2 * EMB + j * 8);
#pragma unroll
      for (int i = 0; i < 8; ++i) VT[(j * 8 + i) * 40 + key] = (u16)v[i];
    }
    __syncthreads();
    // ---- QK^T: S[16q][32k] in two 16-key fragments
    const int key0 = l15, key1 = 16 + l15;
    s16x8 kf00 = *(const s16x8*)&Klds[key0 * 64 + (((0 + g4) ^ (key0 & 7)) * 8)];
    s16x8 kf01 = *(const s16x8*)&Klds[key0 * 64 + (((4 + g4) ^ (key0 & 7)) * 8)];
    s16x8 kf10 = *(const s16x8*)&Klds[key1 * 64 + (((0 + g4) ^ (key1 & 7)) * 8)];
    s16x8 kf11 = *(const s16x8*)&Klds[key1 * 64 + (((4 + g4) ^ (key1 & 7)) * 8)];
    f32x4 z = f32x4{0.f, 0.f, 0.f, 0.f};
    f32x4 s0 = MFMA_16x16x32_BF16(qf0, kf00, z, 0, 0, 0);
    s0 = MFMA_16x16x32_BF16(qf1, kf01, s0, 0, 0, 0);
    f32x4 s1 = MFMA_16x16x32_BF16(qf0, kf10, z, 0, 0, 0);
    s1 = MFMA_16x16x32_BF16(qf1, kf11, s1, 0, 0, 0);
    // ---- online softmax (scale 0.125 folded into exp arg)
#pragma unroll
    for (int r_ = 0; r_ < 4; ++r_) {
      float mx = fmaxf(s0[r_], s1[r_]);
      mx = fmaxf(mx, __shfl_xor(mx, 1));
      mx = fmaxf(mx, __shfl_xor(mx, 2));
      mx = fmaxf(mx, __shfl_xor(mx, 4));
      mx = fmaxf(mx, __shfl_xor(mx, 8));
      float mnew = fmaxf(mrow[r_], mx);
      float alpha = __expf((mrow[r_] - mnew) * 0.125f);
      mrow[r_] = mnew;
      float p0 = __expf((s0[r_] - mnew) * 0.125f);
      float p1 = __expf((s1[r_] - mnew) * 0.125f);
      float ts = p0 + p1;
      ts += __shfl_xor(ts, 1);
      ts += __shfl_xor(ts, 2);
      ts += __shfl_xor(ts, 4);
      ts += __shfl_xor(ts, 8);
      lrow[r_] = lrow[r_] * alpha + ts;
      of[0][r_] *= alpha; of[1][r_] *= alpha;
      of[2][r_] *= alpha; of[3][r_] *= alpha;
      int row = g4 * 4 + r_;
      int sw = (row >> 1) & 3;
      int c0 = (l15 >> 3) ^ sw;
      int c1 = (2 + (l15 >> 3)) ^ sw;
      Pw[(row * 4 + c0) * 8 + (l15 & 7)] = f2bf(p0);
      Pw[(row * 4 + c1) * 8 + (l15 & 7)] = f2bf(p1);
    }
    // ---- PV
    {
      int pchunk = (l15 << 2) | (g4 ^ ((l15 >> 1) & 3));
      s16x8 pf = *(const s16x8*)&Pw[pchunk * 8];
#pragma unroll
      for (int n = 0; n < 4; ++n) {
        s16x8 vf = *(const s16x8*)&VT[(n * 16 + l15) * 40 + g4 * 8];
        of[n] = MFMA_16x16x32_BF16(pf, vf, of[n], 0, 0, 0);
      }
    }
    __syncthreads();
  }
  // ---- epilogue: o = of / l -> bf16
#pragma unroll
  for (int r_ = 0; r_ < 4; ++r_) {
    float inv = 1.f / lrow[r_];
    int qrow = q0 + g4 * 4 + r_;
    size_t ob = (size_t)(b * SEQ + qrow) * EMB + h * 64;
#pragma unroll
    for (int n = 0; n < 4; ++n)
      oHi[ob + n * 16 + l15] = f2bf(of[n][r_] * inv);
  }
}

// ---------------------------------------------------------------------------
extern "C" void kernel_launch(void* const* d_in, const int* in_sizes, int n_in,
                              void* d_out, int out_size, void* d_ws, size_t ws_size,
                              hipStream_t stream) {
  const float* image1     = (const float*)d_in[0];
  const float* image2     = (const float*)d_in[1];
  const float* text_feat  = (const float*)d_in[2];
  const float* mlp_kernel = (const float*)d_in[3];
  const float* mlp_bias   = (const float*)d_in[4];
  const float* ln1_scale  = (const float*)d_in[5];
  const float* ln1_bias   = (const float*)d_in[6];
  const float* qkv_kernel = (const float*)d_in[7];
  const float* qkv_bias   = (const float*)d_in[8];
  const float* proj_kernel= (const float*)d_in[9];
  const float* proj_bias  = (const float*)d_in[10];
  const float* ln2_scale  = (const float*)d_in[11];
  const float* ln2_bias   = (const float*)d_in[12];
  const float* fc1_kernel = (const float*)d_in[13];
  const float* fc2_kernel = (const float*)d_in[14];
  const float* lnf_scale  = (const float*)d_in[15];
  const float* lnf_bias   = (const float*)d_in[16];

  // ---- workspace layout (bytes), ~131 MB total
  size_t off = 0;
  auto take = [&](size_t bytes) { size_t o = off; off += (bytes + 255) & ~(size_t)255; return o; };
  char* ws = (char*)d_ws;
  const size_t oX    = take((size_t)TOKENS * EMB * 4);       // 64 MB residual (f32)
  const size_t oPos  = take((size_t)SEQ * EMB * 4);          //  2 MB
  const size_t oHHi  = take((size_t)CH * EMB * 2);           //  8 MB
  const size_t oOHi  = take((size_t)CH * EMB * 2);           //  8 MB
  const size_t oBig  = take((size_t)CH * MLPD * 2);          // 32 MB (feats | qkv | m)
  const size_t oWbuf = take((size_t)2 * 8 * 1024 * 1024);    // 16 MB (2 x 8MB weight slots)
  if (off > ws_size) {  // diagnostic: absmax ~1e6 next round => ws too small
    fill_kernel<<<(out_size + 255) / 256, 256, 0, stream>>>((float*)d_out, out_size);
    return;
  }

  float* x   = (float*)(ws + oX);
  float* pos = (float*)(ws + oPos);
  u16* hHi   = (u16*)(ws + oHHi);
  u16* oHi   = (u16*)(ws + oOHi);
  u16* big   = (u16*)(ws + oBig);
  u16* s0    = (u16*)(ws + oWbuf);
  u16* s1    = s0 + (size_t)4 * 1024 * 1024;   // second 8MB slot (u16 units)

  pos_kernel<<<SEQ, 256, 0, stream>>>(pos);

  // ---- MLP-in: x = concat(feats) @ W1 + b + pos, chunked
  wtrans_kernel<<<dim3(EMB / 64, K1 / 64), 256, 0, stream>>>(mlp_kernel, s0, K1, EMB);
  for (int c = 0; c < NCH; ++c) {
    const size_t fo = (size_t)c * CH * 512;
    concat_kernel<<<CH * K1 / 1024, 256, 0, stream>>>(image1 + fo, image2 + fo, text_feat + fo, big);
    gemm1_kernel<0><<<dim3(CH / 128, EMB / 128), 256, 0, stream>>>(
        big, s0, K1, EMB, mlp_bias, pos, x + (size_t)c * CH * EMB, nullptr);
  }

  for (int i = 0; i < DEPTH; ++i) {
    // ---- attention phase: qkv weights -> s0, proj -> s1
    wtrans_kernel<<<dim3(H3 / 64, EMB / 64), 256, 0, stream>>>(
        qkv_kernel + (size_t)i * EMB * H3, s0, EMB, H3);
    wtrans_kernel<<<dim3(EMB / 64, EMB / 64), 256, 0, stream>>>(
        proj_kernel + (size_t)i * EMB * EMB, s1, EMB, EMB);
    for (int c = 0; c < NCH; ++c) {
      float* xc = x + (size_t)c * CH * EMB;
      ln_kernel<0><<<CH / 4, 256, 0, stream>>>(xc, ln1_scale + i * EMB, ln1_bias + i * EMB,
                                               hHi, nullptr);
      gemm1_kernel<1><<<dim3(CH / 128, H3 / 128), 256, 0, stream>>>(
          hHi, s0, EMB, H3, qkv_bias + i * H3, nullptr, nullptr, big);
      attn_kernel<<<dim3(SEQ / 64, HEADS, CB), 256, 0, stream>>>(big, oHi);
      gemm1_kernel<2><<<dim3(CH / 128, EMB / 128), 256, 0, stream>>>(
          oHi, s1, EMB, EMB, proj_bias + i * EMB, xc, xc, nullptr);
    }
    // ---- MLP phase: fc1 -> s0, fc2 -> s1
    wtrans_kernel<<<dim3(MLPD / 64, EMB / 64), 256, 0, stream>>>(
        fc1_kernel + (size_t)i * EMB * MLPD, s0, EMB, MLPD);
    wtrans_kernel<<<dim3(EMB / 64, MLPD / 64), 256, 0, stream>>>(
        fc2_kernel + (size_t)i * MLPD * EMB, s1, MLPD, EMB);
    for (int c = 0; c < NCH; ++c) {
      float* xc = x + (size_t)c * CH * EMB;
      ln_kernel<0><<<CH / 4, 256, 0, stream>>>(xc, ln2_scale + i * EMB, ln2_bias + i * EMB,
                                               hHi, nullptr);
      gemm1_kernel<3><<<dim3(CH / 128, MLPD / 128), 256, 0, stream>>>(
          hHi, s0, EMB, MLPD, nullptr, nullptr, nullptr, big);
      gemm1_kernel<4><<<dim3(CH / 128, EMB / 128), 256, 0, stream>>>(
          big, s1, MLPD, EMB, nullptr, xc, xc, nullptr);
    }
  }
  ln_kernel<1><<<TOKENS / 4, 256, 0, stream>>>(x, lnf_scale, lnf_bias,
                                               nullptr, (float*)d_out);
}

// Round 7
// 3479.485 us; speedup vs baseline: 2.2180x; 1.1524x over previous
//
#include <hip/hip_runtime.h>
#include <hip/hip_bf16.h>
#include <stdint.h>

#define SEQ     512
#define BATCH   32
#define TOKENS  16384   // BATCH*SEQ
#define EMB     1024
#define HEADS   16
#define DEPTH   4
#define K1      1536    // 3*F
#define H3      3072
#define MLPD    4096
#define CH      8192    // tokens per processing chunk (attn/qkv phase)
#define NCH     (TOKENS / CH)
#define CB      (CH / SEQ)   // batches per chunk = 16

typedef unsigned short u16;
typedef __attribute__((ext_vector_type(4))) float  f32x4;
typedef __attribute__((ext_vector_type(8))) short  s16x8;
typedef __attribute__((ext_vector_type(4))) u16    u16x4;

#define MFMA_16x16x32_BF16 __builtin_amdgcn_mfma_f32_16x16x32_bf16

__device__ __forceinline__ u16 f2bf(float f) {
  union { float f; uint32_t i; } c; c.f = f;
  uint32_t u = c.i;
  u += 0x7FFFu + ((u >> 16) & 1u);   // RNE
  return (u16)(u >> 16);
}
__device__ __forceinline__ void gll16(const void* g, void* l) {
  __builtin_amdgcn_global_load_lds(
      (const __attribute__((address_space(1))) uint32_t*)g,
      (__attribute__((address_space(3))) uint32_t*)l, 16, 0, 0);
}

// ---------------------------------------------------------------------------
// Diagnostic fill (used only when ws_size is insufficient)
// ---------------------------------------------------------------------------
__global__ __launch_bounds__(256)
void fill_kernel(float* __restrict__ out, int n) {
  int i = blockIdx.x * 256 + threadIdx.x;
  if (i < n) out[i] = 1.0e6f;
}

// ---------------------------------------------------------------------------
// Weight transpose + bf16 round:  W[K][N] f32  ->  Wt [N][K] bf16
// grid: (N/64, K/64), 256 threads
// ---------------------------------------------------------------------------
__global__ __launch_bounds__(256)
void wtrans_kernel(const float* __restrict__ W, u16* __restrict__ oHi,
                   int K, int N) {
  const int n0 = blockIdx.x * 64, k0 = blockIdx.y * 64;
  __shared__ float tile[64][65];
  const int t = threadIdx.x;
  const int tr = t >> 4, tc4 = (t & 15) * 4;
#pragma unroll
  for (int rr = 0; rr < 4; ++rr) {
    int r = tr + rr * 16;
    const float4 v = *(const float4*)&W[(size_t)(k0 + r) * N + n0 + tc4];
    tile[r][tc4 + 0] = v.x; tile[r][tc4 + 1] = v.y;
    tile[r][tc4 + 2] = v.z; tile[r][tc4 + 3] = v.w;
  }
  __syncthreads();
#pragma unroll
  for (int rr = 0; rr < 4; ++rr) {
    int n = tr + rr * 16;
    u16x4 vh;
#pragma unroll
    for (int j = 0; j < 4; ++j) vh[j] = f2bf(tile[tc4 + j][n]);
    size_t o = (size_t)(n0 + n) * K + k0 + tc4;
    *(u16x4*)&oHi[o] = vh;
  }
}

// ---------------------------------------------------------------------------
// Concat 3 feature streams -> bf16 [CH][1536], one CH-token chunk.
// ---------------------------------------------------------------------------
__global__ __launch_bounds__(256)
void concat_kernel(const float* __restrict__ i1, const float* __restrict__ i2,
                   const float* __restrict__ tf, u16* __restrict__ fHi) {
  size_t gid = (size_t)blockIdx.x * 256 + threadIdx.x;
  size_t e = gid * 4;
  int m = (int)(e / K1), c = (int)(e % K1);
  const float* src = (c < 512) ? i1 : ((c < 1024) ? i2 : tf);
  const float4 v = *(const float4*)&src[(size_t)m * 512 + (c & 511)];
  u16x4 vh;
  vh[0] = f2bf(v.x); vh[1] = f2bf(v.y); vh[2] = f2bf(v.z); vh[3] = f2bf(v.w);
  *(u16x4*)&fHi[(size_t)m * K1 + c] = vh;
}

// ---------------------------------------------------------------------------
// sincos positional embedding table [512][1024] f32
// ---------------------------------------------------------------------------
__global__ __launch_bounds__(256)
void pos_kernel(float* __restrict__ pos) {
  const int t = blockIdx.x;
#pragma unroll
  for (int p = 0; p < 2; ++p) {
    int d = threadIdx.x + p * 256;              // 0..511
    double omega = pow(10000.0, -(double)d / 512.0);
    double v = (double)t * omega;
    pos[(size_t)t * EMB + d]       = (float)sin(v);
    pos[(size_t)t * EMB + 512 + d] = (float)cos(v);
  }
}

// ---------------------------------------------------------------------------
// LayerNorm over 1024; one wave per row. OUTF=0: bf16 out, 1: f32 out.
// ---------------------------------------------------------------------------
template <int OUTF>
__global__ __launch_bounds__(256)
void ln_kernel(const float* __restrict__ x, const float* __restrict__ scale,
               const float* __restrict__ bias, u16* __restrict__ hHi,
               float* __restrict__ outF) {
  const int w = threadIdx.x >> 6, lane = threadIdx.x & 63;
  const int row = blockIdx.x * 4 + w;
  const float* xr = x + (size_t)row * EMB;
  float4 vv[4];
  float s = 0.f, s2 = 0.f;
#pragma unroll
  for (int j = 0; j < 4; ++j) {
    vv[j] = *(const float4*)&xr[j * 256 + lane * 4];
    s  += vv[j].x + vv[j].y + vv[j].z + vv[j].w;
    s2 += vv[j].x * vv[j].x + vv[j].y * vv[j].y + vv[j].z * vv[j].z + vv[j].w * vv[j].w;
  }
#pragma unroll
  for (int m = 1; m < 64; m <<= 1) {
    s  += __shfl_xor(s, m);
    s2 += __shfl_xor(s2, m);
  }
  const float mu = s * (1.f / EMB);
  const float var = s2 * (1.f / EMB) - mu * mu;
  const float rs = rsqrtf(var + 1e-6f);
#pragma unroll
  for (int j = 0; j < 4; ++j) {
    int c = j * 256 + lane * 4;
    const float4 sc = *(const float4*)&scale[c];
    const float4 bi = *(const float4*)&bias[c];
    float h0 = (vv[j].x - mu) * rs * sc.x + bi.x;
    float h1 = (vv[j].y - mu) * rs * sc.y + bi.y;
    float h2 = (vv[j].z - mu) * rs * sc.z + bi.z;
    float h3 = (vv[j].w - mu) * rs * sc.w + bi.w;
    size_t o = (size_t)row * EMB + c;
    if (OUTF) {
      *(float4*)&outF[o] = make_float4(h0, h1, h2, h3);
    } else {
      u16x4 vh;
      vh[0] = f2bf(h0); vh[1] = f2bf(h1); vh[2] = f2bf(h2); vh[3] = f2bf(h3);
      *(u16x4*)&hHi[o] = vh;
    }
  }
}

// ---------------------------------------------------------------------------
// 128x128-tile bf16 GEMM (2-phase dbuf) — retained for MLP-in (EPI 0 only).
// ---------------------------------------------------------------------------
template <int EPI>
__global__ __launch_bounds__(256, 3)
void gemm1_kernel(const u16* __restrict__ A, const u16* __restrict__ B,
                  int K, int N, const float* __restrict__ bias,
                  const float* __restrict__ extra, float* __restrict__ outF,
                  u16* __restrict__ outHi) {
  const int tid = threadIdx.x;
  const int lane = tid & 63;
  const int w = tid >> 6;
  const int wm = w >> 1, wn = w & 1;
  const int bm = blockIdx.x * 128, bn = blockIdx.y * 128;
  const int l15 = lane & 15, g4 = lane >> 4;

  __shared__ u16 lds[16384];

  f32x4 acc[4][4];
#pragma unroll
  for (int i = 0; i < 4; ++i)
#pragma unroll
    for (int j = 0; j < 4; ++j) acc[i][j] = f32x4{0.f, 0.f, 0.f, 0.f};

  auto stage = [&](int buf, int k0) {
#pragma unroll
    for (int p = 0; p < 2; ++p) {
      int c = p * 256 + tid;
      int r = c >> 2;
      int gg = (c & 3) ^ ((r >> 1) & 3);
      gll16(A + (size_t)(bm + r) * K + k0 + gg * 8, &lds[buf * 8192 + c * 8]);
      gll16(B + (size_t)(bn + r) * K + k0 + gg * 8, &lds[buf * 8192 + 4096 + c * 8]);
    }
  };

  const int nk = K >> 5;
  stage(0, 0);
  for (int kt = 0; kt < nk; ++kt) {
    const int cur = kt & 1;
    __syncthreads();
    if (kt + 1 < nk) stage(cur ^ 1, (kt + 1) * 32);
    s16x8 ah[4], bh[4];
#pragma unroll
    for (int mi = 0; mi < 4; ++mi) {
      int r = wm * 64 + mi * 16 + l15;
      int chunk = (r << 2) | (g4 ^ ((r >> 1) & 3));
      ah[mi] = *(const s16x8*)&lds[cur * 8192 + chunk * 8];
    }
#pragma unroll
    for (int ni = 0; ni < 4; ++ni) {
      int r = wn * 64 + ni * 16 + l15;
      int chunk = (r << 2) | (g4 ^ ((r >> 1) & 3));
      bh[ni] = *(const s16x8*)&lds[cur * 8192 + 4096 + chunk * 8];
    }
#pragma unroll
    for (int mi = 0; mi < 4; ++mi)
#pragma unroll
      for (int ni = 0; ni < 4; ++ni)
        acc[mi][ni] = MFMA_16x16x32_BF16(ah[mi], bh[ni], acc[mi][ni], 0, 0, 0);
  }
#pragma unroll
  for (int mi = 0; mi < 4; ++mi) {
#pragma unroll
    for (int ni = 0; ni < 4; ++ni) {
      int gc = bn + wn * 64 + ni * 16 + l15;
      float bv = (EPI == 0 || EPI == 1 || EPI == 2) ? bias[gc] : 0.f;
#pragma unroll
      for (int r_ = 0; r_ < 4; ++r_) {
        int gr = bm + wm * 64 + mi * 16 + g4 * 4 + r_;
        float v = acc[mi][ni][r_] + bv;
        size_t o = (size_t)gr * N + gc;
        if (EPI == 0) {
          outF[o] = v + extra[(size_t)(gr & (SEQ - 1)) * EMB + gc];
        } else if (EPI == 1) {
          outHi[o] = f2bf(v);
        } else if (EPI == 2 || EPI == 4) {
          outF[o] = v + extra[o];
        } else {
          float t3 = v + 0.044715f * v * v * v;
          float gl = 0.5f * v * (1.f + tanhf(0.7978845608028654f * t3));
          outHi[o] = f2bf(gl);
        }
      }
    }
  }
}

// ---------------------------------------------------------------------------
// 256x256-tile bf16 GEMM, 8 waves (2M x 4N), BK=32, double-buffered 64 KiB LDS.
// T3 minimum 2-phase recipe: issue next-tile stage at loop top, ds_read+MFMA
// current tile, ONE __syncthreads() per K-step (drains vmcnt+lgkmcnt with
// compiler-enforced ordering). setprio(1) around MFMA clusters.
// Per wave: 128x64 output = 8x4 fragments. Granule-XOR swizzle (g ^= r&3).
// EPI: 1 = +bias -> bf16 (QKV); 2 = +bias +res -> f32 (proj);
//      3 = gelu -> bf16 (fc1); 4 = +res -> f32 (fc2 accumulate).
// Requires M%256==0, N%256==0, K%32==0.
// ---------------------------------------------------------------------------
template <int EPI>
__global__ __launch_bounds__(512, 2)
void gemm8_kernel(const u16* __restrict__ A, const u16* __restrict__ B,
                  int K, int N, const float* __restrict__ bias,
                  const float* __restrict__ extra, float* __restrict__ outF,
                  u16* __restrict__ outHi) {
  const int tid = threadIdx.x;              // 0..511
  const int lane = tid & 63, w = tid >> 6;  // 8 waves
  const int wm = w >> 2, wn = w & 3;        // 2 x 4
  const int bm = blockIdx.x * 256, bn = blockIdx.y * 256;
  const int l15 = lane & 15, g4 = lane >> 4;

  // buf c: A-tile [256][32] @ c*16384 u16, B-tile @ c*16384+8192. Total 64 KiB.
  __shared__ u16 lds8[32768];

  f32x4 acc[8][4];
#pragma unroll
  for (int i = 0; i < 8; ++i)
#pragma unroll
    for (int j = 0; j < 4; ++j) acc[i][j] = f32x4{0.f, 0.f, 0.f, 0.f};

  // Stage one full 256x32 tile (= 1024 x 16B chunks; 2 chunks per thread).
  // Linear LDS dest (wave-uniform + lane*16B); source granule pre-swizzled
  // gg = g ^ (r&3) to match the swizzled reads below.
  auto stage32 = [&](int buf, int k0, int isB) {
    const u16* src = isB ? B : A;
    const int rowBase = isB ? bn : bm;
    const int base = buf * 16384 + isB * 8192;
#pragma unroll
    for (int p = 0; p < 2; ++p) {
      int c = p * 512 + tid;          // chunk 0..1023
      int r = c >> 2;                 // row 0..255
      int gg = (c & 3) ^ (r & 3);
      gll16(src + (size_t)(rowBase + r) * K + k0 + gg * 8, &lds8[base + c * 8]);
    }
  };

  const int NK = K >> 5;
  stage32(0, 0, 0);
  stage32(0, 0, 1);
  __syncthreads();
  for (int kt = 0; kt < NK; ++kt) {
    const int cu = kt & 1;
    const int ab = cu * 16384;
    const int bb = ab + 8192;
    if (kt + 1 < NK) {                 // issue next-tile loads first
      const int k1 = (kt + 1) << 5;
      stage32(cu ^ 1, k1, 0);
      stage32(cu ^ 1, k1, 1);
    }
    s16x8 Bf[4], Af[4];
#pragma unroll
    for (int ni = 0; ni < 4; ++ni) {
      int r = wn * 64 + ni * 16 + l15;
      Bf[ni] = *(const s16x8*)&lds8[bb + ((r << 2) | (g4 ^ (r & 3))) * 8];
    }
#pragma unroll
    for (int mi = 0; mi < 4; ++mi) {
      int r = wm * 128 + mi * 16 + l15;
      Af[mi] = *(const s16x8*)&lds8[ab + ((r << 2) | (g4 ^ (r & 3))) * 8];
    }
    __builtin_amdgcn_s_setprio(1);
#pragma unroll
    for (int mi = 0; mi < 4; ++mi)
#pragma unroll
      for (int ni = 0; ni < 4; ++ni)
        acc[mi][ni] = MFMA_16x16x32_BF16(Af[mi], Bf[ni], acc[mi][ni], 0, 0, 0);
    __builtin_amdgcn_s_setprio(0);
#pragma unroll
    for (int mi = 0; mi < 4; ++mi) {
      int r = wm * 128 + 64 + mi * 16 + l15;
      Af[mi] = *(const s16x8*)&lds8[ab + ((r << 2) | (g4 ^ (r & 3))) * 8];
    }
    __builtin_amdgcn_s_setprio(1);
#pragma unroll
    for (int mi = 0; mi < 4; ++mi)
#pragma unroll
      for (int ni = 0; ni < 4; ++ni)
        acc[4 + mi][ni] = MFMA_16x16x32_BF16(Af[mi], Bf[ni], acc[4 + mi][ni], 0, 0, 0);
    __builtin_amdgcn_s_setprio(0);
    __syncthreads();                   // one barrier per K-step
  }
  // ---- epilogue: C/D layout row=(lane>>4)*4+reg, col=lane&15 ----
#pragma unroll
  for (int fm = 0; fm < 8; ++fm) {
#pragma unroll
    for (int ni = 0; ni < 4; ++ni) {
      int gc = bn + wn * 64 + ni * 16 + l15;
      float bv = (EPI == 1 || EPI == 2) ? bias[gc] : 0.f;
#pragma unroll
      for (int r_ = 0; r_ < 4; ++r_) {
        int gr = bm + wm * 128 + fm * 16 + g4 * 4 + r_;
        float v = acc[fm][ni][r_] + bv;
        size_t o = (size_t)gr * N + gc;
        if (EPI == 1) {
          outHi[o] = f2bf(v);
        } else if (EPI == 2 || EPI == 4) {
          outF[o] = v + extra[o];
        } else {  // EPI == 3: tanh-approx GELU -> bf16
          float t3 = v + 0.044715f * v * v * v;
          float gl = 0.5f * v * (1.f + tanhf(0.7978845608028654f * t3));
          outHi[o] = f2bf(gl);
        }
      }
    }
  }
}

// ---------------------------------------------------------------------------
// Flash attention fwd, one CH-token chunk (CB batches). grid (SEQ/64, HEADS, CB),
// 256 thr = 4 waves, each wave owns 16 q-rows. qkv: bf16 [CH][3072] (q|k|v).
// ---------------------------------------------------------------------------
__global__ __launch_bounds__(256, 2)
void attn_kernel(const u16* __restrict__ qkv, u16* __restrict__ oHi) {
  const int qb = blockIdx.x, h = blockIdx.y, b = blockIdx.z;
  const int tid = threadIdx.x, lane = tid & 63, w = tid >> 6;
  const int l15 = lane & 15, g4 = lane >> 4;

  __shared__ u16 smem[2048 + 2560 + 2048];
  u16* Klds = smem;
  u16* VT   = smem + 2048;
  u16* Pw   = smem + 2048 + 2560 + w * 512;

  const int q0 = qb * 64 + w * 16;
  const size_t base = (size_t)b * SEQ * H3 + (size_t)h * 64;

  s16x8 qf0, qf1;
  {
    const u16* qp = qkv + base + (size_t)(q0 + l15) * H3 + g4 * 8;
    qf0 = *(const s16x8*)qp;
    qf1 = *(const s16x8*)(qp + 32);
  }

  f32x4 of[4];
#pragma unroll
  for (int n = 0; n < 4; ++n) of[n] = f32x4{0.f, 0.f, 0.f, 0.f};
  float mrow[4] = {-1e30f, -1e30f, -1e30f, -1e30f};
  float lrow[4] = {0.f, 0.f, 0.f, 0.f};

  for (int kt = 0; kt < SEQ; kt += 32) {
    {
      int r = tid >> 3;
      int jj = (tid & 7) ^ (r & 7);
      gll16(qkv + base + (size_t)(kt + r) * H3 + EMB + jj * 8, &Klds[tid * 8]);
    }
    {
      int key = tid >> 3, j = tid & 7;
      s16x8 v = *(const s16x8*)(qkv + base + (size_t)(kt + key) * H3 + 2 * EMB + j * 8);
#pragma unroll
      for (int i = 0; i < 8; ++i) VT[(j * 8 + i) * 40 + key] = (u16)v[i];
    }
    __syncthreads();
    const int key0 = l15, key1 = 16 + l15;
    s16x8 kf00 = *(const s16x8*)&Klds[key0 * 64 + (((0 + g4) ^ (key0 & 7)) * 8)];
    s16x8 kf01 = *(const s16x8*)&Klds[key0 * 64 + (((4 + g4) ^ (key0 & 7)) * 8)];
    s16x8 kf10 = *(const s16x8*)&Klds[key1 * 64 + (((0 + g4) ^ (key1 & 7)) * 8)];
    s16x8 kf11 = *(const s16x8*)&Klds[key1 * 64 + (((4 + g4) ^ (key1 & 7)) * 8)];
    f32x4 z = f32x4{0.f, 0.f, 0.f, 0.f};
    f32x4 s0 = MFMA_16x16x32_BF16(qf0, kf00, z, 0, 0, 0);
    s0 = MFMA_16x16x32_BF16(qf1, kf01, s0, 0, 0, 0);
    f32x4 s1 = MFMA_16x16x32_BF16(qf0, kf10, z, 0, 0, 0);
    s1 = MFMA_16x16x32_BF16(qf1, kf11, s1, 0, 0, 0);
#pragma unroll
    for (int r_ = 0; r_ < 4; ++r_) {
      float mx = fmaxf(s0[r_], s1[r_]);
      mx = fmaxf(mx, __shfl_xor(mx, 1));
      mx = fmaxf(mx, __shfl_xor(mx, 2));
      mx = fmaxf(mx, __shfl_xor(mx, 4));
      mx = fmaxf(mx, __shfl_xor(mx, 8));
      float mnew = fmaxf(mrow[r_], mx);
      float alpha = __expf((mrow[r_] - mnew) * 0.125f);
      mrow[r_] = mnew;
      float p0 = __expf((s0[r_] - mnew) * 0.125f);
      float p1 = __expf((s1[r_] - mnew) * 0.125f);
      float ts = p0 + p1;
      ts += __shfl_xor(ts, 1);
      ts += __shfl_xor(ts, 2);
      ts += __shfl_xor(ts, 4);
      ts += __shfl_xor(ts, 8);
      lrow[r_] = lrow[r_] * alpha + ts;
      of[0][r_] *= alpha; of[1][r_] *= alpha;
      of[2][r_] *= alpha; of[3][r_] *= alpha;
      int row = g4 * 4 + r_;
      int sw = (row >> 1) & 3;
      int c0 = (l15 >> 3) ^ sw;
      int c1 = (2 + (l15 >> 3)) ^ sw;
      Pw[(row * 4 + c0) * 8 + (l15 & 7)] = f2bf(p0);
      Pw[(row * 4 + c1) * 8 + (l15 & 7)] = f2bf(p1);
    }
    {
      int pchunk = (l15 << 2) | (g4 ^ ((l15 >> 1) & 3));
      s16x8 pf = *(const s16x8*)&Pw[pchunk * 8];
#pragma unroll
      for (int n = 0; n < 4; ++n) {
        s16x8 vf = *(const s16x8*)&VT[(n * 16 + l15) * 40 + g4 * 8];
        of[n] = MFMA_16x16x32_BF16(pf, vf, of[n], 0, 0, 0);
      }
    }
    __syncthreads();
  }
#pragma unroll
  for (int r_ = 0; r_ < 4; ++r_) {
    float inv = 1.f / lrow[r_];
    int qrow = q0 + g4 * 4 + r_;
    size_t ob = (size_t)(b * SEQ + qrow) * EMB + h * 64;
#pragma unroll
    for (int n = 0; n < 4; ++n)
      oHi[ob + n * 16 + l15] = f2bf(of[n][r_] * inv);
  }
}

// ---------------------------------------------------------------------------
extern "C" void kernel_launch(void* const* d_in, const int* in_sizes, int n_in,
                              void* d_out, int out_size, void* d_ws, size_t ws_size,
                              hipStream_t stream) {
  const float* image1     = (const float*)d_in[0];
  const float* image2     = (const float*)d_in[1];
  const float* text_feat  = (const float*)d_in[2];
  const float* mlp_kernel = (const float*)d_in[3];
  const float* mlp_bias   = (const float*)d_in[4];
  const float* ln1_scale  = (const float*)d_in[5];
  const float* ln1_bias   = (const float*)d_in[6];
  const float* qkv_kernel = (const float*)d_in[7];
  const float* qkv_bias   = (const float*)d_in[8];
  const float* proj_kernel= (const float*)d_in[9];
  const float* proj_bias  = (const float*)d_in[10];
  const float* ln2_scale  = (const float*)d_in[11];
  const float* ln2_bias   = (const float*)d_in[12];
  const float* fc1_kernel = (const float*)d_in[13];
  const float* fc2_kernel = (const float*)d_in[14];
  const float* lnf_scale  = (const float*)d_in[15];
  const float* lnf_bias   = (const float*)d_in[16];

  // ---- workspace layout (bytes), ~178 MiB total (< proven 194 MiB)
  size_t off = 0;
  auto take = [&](size_t bytes) { size_t o = off; off += (bytes + 255) & ~(size_t)255; return o; };
  char* ws = (char*)d_ws;
  const size_t oX    = take((size_t)TOKENS * EMB * 4);            // 64 MiB residual f32
  const size_t oPos  = take((size_t)SEQ * EMB * 4);               //  2 MiB
  const size_t oSh   = take((size_t)TOKENS * EMB * 2);            // 32 MiB: attn-out | hFull (MLP)
  const size_t oBig  = take((size_t)CH * H3 * 2 + (size_t)CH * EMB * 2); // 64 MiB: qkv(48)+hChunk(16) | fc1half(64) | feats(24)
  const size_t oWbuf = take((size_t)16 * 1024 * 1024);            // 16 MiB weight slots
  if (off > ws_size) {  // diagnostic: absmax ~1e6 next round => ws too small
    fill_kernel<<<(out_size + 255) / 256, 256, 0, stream>>>((float*)d_out, out_size);
    return;
  }

  float* x   = (float*)(ws + oX);
  float* pos = (float*)(ws + oPos);
  u16* shrd  = (u16*)(ws + oSh);
  u16* oA    = shrd;                            // attention output (full), attn phase
  u16* hFull = shrd;                            // LN2 output (full), MLP phase
  u16* big   = (u16*)(ws + oBig);
  u16* hC    = big + (size_t)CH * H3;           // per-chunk LN1 out, tail 16 MiB of big
  u16* wbuf  = (u16*)(ws + oWbuf);
  u16* wq  = wbuf;                              // 6 MiB [3072][1024]
  u16* wp  = wbuf + (size_t)3 * 1024 * 1024;    // 2 MiB [1024][1024]
  u16* wf1 = wbuf;                              // 8 MiB [4096][1024]
  u16* wf2 = wbuf + (size_t)4 * 1024 * 1024;    // 4 MiB [1024][2048]
  u16* w1t = wbuf;                              // 3 MiB [1024][1536]

  pos_kernel<<<SEQ, 256, 0, stream>>>(pos);

  // ---- MLP-in: x = concat(feats) @ W1 + b + pos (128^2 kernel, chunked)
  wtrans_kernel<<<dim3(EMB / 64, K1 / 64), 256, 0, stream>>>(mlp_kernel, w1t, K1, EMB);
  for (int c = 0; c < NCH; ++c) {
    const size_t fo = (size_t)c * CH * 512;
    concat_kernel<<<CH * K1 / 1024, 256, 0, stream>>>(image1 + fo, image2 + fo, text_feat + fo, big);
    gemm1_kernel<0><<<dim3(CH / 128, EMB / 128), 256, 0, stream>>>(
        big, w1t, K1, EMB, mlp_bias, pos, x + (size_t)c * CH * EMB, nullptr);
  }

  for (int i = 0; i < DEPTH; ++i) {
    // ---- attention: qkvT -> wq, projT -> wp
    wtrans_kernel<<<dim3(H3 / 64, EMB / 64), 256, 0, stream>>>(
        qkv_kernel + (size_t)i * EMB * H3, wq, EMB, H3);
    wtrans_kernel<<<dim3(EMB / 64, EMB / 64), 256, 0, stream>>>(
        proj_kernel + (size_t)i * EMB * EMB, wp, EMB, EMB);
    for (int c = 0; c < NCH; ++c) {
      float* xc = x + (size_t)c * CH * EMB;
      ln_kernel<0><<<CH / 4, 256, 0, stream>>>(xc, ln1_scale + i * EMB, ln1_bias + i * EMB,
                                               hC, nullptr);
      gemm8_kernel<1><<<dim3(CH / 256, H3 / 256), 512, 0, stream>>>(
          hC, wq, EMB, H3, qkv_bias + i * H3, nullptr, nullptr, big);
      attn_kernel<<<dim3(SEQ / 64, HEADS, CB), 256, 0, stream>>>(big, oA + (size_t)c * CH * EMB);
    }
    gemm8_kernel<2><<<dim3(TOKENS / 256, EMB / 256), 512, 0, stream>>>(
        oA, wp, EMB, EMB, proj_bias + i * EMB, x, x, nullptr);
    // ---- MLP: hFull = LN2(x) ONCE (before any fc2 accumulate touches x)
    ln_kernel<0><<<TOKENS / 4, 256, 0, stream>>>(x, ln2_scale + i * EMB, ln2_bias + i * EMB,
                                                 hFull, nullptr);
    wtrans_kernel<<<dim3(MLPD / 64, EMB / 64), 256, 0, stream>>>(
        fc1_kernel + (size_t)i * EMB * MLPD, wf1, EMB, MLPD);
    for (int nh = 0; nh < 2; ++nh) {
      wtrans_kernel<<<dim3(EMB / 64, 2048 / 64), 256, 0, stream>>>(
          fc2_kernel + (size_t)i * MLPD * EMB + (size_t)nh * 2048 * EMB, wf2, 2048, EMB);
      gemm8_kernel<3><<<dim3(TOKENS / 256, 2048 / 256), 512, 0, stream>>>(
          hFull, wf1 + (size_t)nh * 2048 * 1024, EMB, 2048, nullptr, nullptr, nullptr, big);
      gemm8_kernel<4><<<dim3(TOKENS / 256, EMB / 256), 512, 0, stream>>>(
          big, wf2, 2048, EMB, nullptr, x, x, nullptr);
    }
  }
  ln_kernel<1><<<TOKENS / 4, 256, 0, stream>>>(x, lnf_scale, lnf_bias,
                                               nullptr, (float*)d_out);
}

// Round 8
// 3423.356 us; speedup vs baseline: 2.2543x; 1.0164x over previous
//
#include <hip/hip_runtime.h>
#include <hip/hip_bf16.h>
#include <stdint.h>

#define SEQ     512
#define BATCH   32
#define TOKENS  16384   // BATCH*SEQ
#define EMB     1024
#define HEADS   16
#define DEPTH   4
#define K1      1536    // 3*F
#define H3      3072
#define MLPD    4096
#define CH      8192    // tokens per processing chunk (attn/qkv phase)
#define NCH     (TOKENS / CH)
#define CB      (CH / SEQ)   // batches per chunk = 16

typedef unsigned short u16;
typedef __attribute__((ext_vector_type(4))) float  f32x4;
typedef __attribute__((ext_vector_type(8))) short  s16x8;
typedef __attribute__((ext_vector_type(4))) u16    u16x4;

#define MFMA_16x16x32_BF16 __builtin_amdgcn_mfma_f32_16x16x32_bf16

__device__ __forceinline__ u16 f2bf(float f) {
  union { float f; uint32_t i; } c; c.f = f;
  uint32_t u = c.i;
  u += 0x7FFFu + ((u >> 16) & 1u);   // RNE
  return (u16)(u >> 16);
}
__device__ __forceinline__ void gll16(const void* g, void* l) {
  __builtin_amdgcn_global_load_lds(
      (const __attribute__((address_space(1))) uint32_t*)g,
      (__attribute__((address_space(3))) uint32_t*)l, 16, 0, 0);
}

// ---------------------------------------------------------------------------
// Diagnostic fill (used only when ws_size is insufficient)
// ---------------------------------------------------------------------------
__global__ __launch_bounds__(256)
void fill_kernel(float* __restrict__ out, int n) {
  int i = blockIdx.x * 256 + threadIdx.x;
  if (i < n) out[i] = 1.0e6f;
}

// ---------------------------------------------------------------------------
// Weight transpose + bf16 round:  W[K][N] f32  ->  Wt [N][K] bf16
// grid: (N/64, K/64), 256 threads
// ---------------------------------------------------------------------------
__global__ __launch_bounds__(256)
void wtrans_kernel(const float* __restrict__ W, u16* __restrict__ oHi,
                   int K, int N) {
  const int n0 = blockIdx.x * 64, k0 = blockIdx.y * 64;
  __shared__ float tile[64][65];
  const int t = threadIdx.x;
  const int tr = t >> 4, tc4 = (t & 15) * 4;
#pragma unroll
  for (int rr = 0; rr < 4; ++rr) {
    int r = tr + rr * 16;
    const float4 v = *(const float4*)&W[(size_t)(k0 + r) * N + n0 + tc4];
    tile[r][tc4 + 0] = v.x; tile[r][tc4 + 1] = v.y;
    tile[r][tc4 + 2] = v.z; tile[r][tc4 + 3] = v.w;
  }
  __syncthreads();
#pragma unroll
  for (int rr = 0; rr < 4; ++rr) {
    int n = tr + rr * 16;
    u16x4 vh;
#pragma unroll
    for (int j = 0; j < 4; ++j) vh[j] = f2bf(tile[tc4 + j][n]);
    size_t o = (size_t)(n0 + n) * K + k0 + tc4;
    *(u16x4*)&oHi[o] = vh;
  }
}

// ---------------------------------------------------------------------------
// Concat 3 feature streams -> bf16 [CH][1536], one CH-token chunk.
// ---------------------------------------------------------------------------
__global__ __launch_bounds__(256)
void concat_kernel(const float* __restrict__ i1, const float* __restrict__ i2,
                   const float* __restrict__ tf, u16* __restrict__ fHi) {
  size_t gid = (size_t)blockIdx.x * 256 + threadIdx.x;
  size_t e = gid * 4;
  int m = (int)(e / K1), c = (int)(e % K1);
  const float* src = (c < 512) ? i1 : ((c < 1024) ? i2 : tf);
  const float4 v = *(const float4*)&src[(size_t)m * 512 + (c & 511)];
  u16x4 vh;
  vh[0] = f2bf(v.x); vh[1] = f2bf(v.y); vh[2] = f2bf(v.z); vh[3] = f2bf(v.w);
  *(u16x4*)&fHi[(size_t)m * K1 + c] = vh;
}

// ---------------------------------------------------------------------------
// sincos positional embedding table [512][1024] f32
// ---------------------------------------------------------------------------
__global__ __launch_bounds__(256)
void pos_kernel(float* __restrict__ pos) {
  const int t = blockIdx.x;
#pragma unroll
  for (int p = 0; p < 2; ++p) {
    int d = threadIdx.x + p * 256;              // 0..511
    double omega = pow(10000.0, -(double)d / 512.0);
    double v = (double)t * omega;
    pos[(size_t)t * EMB + d]       = (float)sin(v);
    pos[(size_t)t * EMB + 512 + d] = (float)cos(v);
  }
}

// ---------------------------------------------------------------------------
// LayerNorm over 1024; one wave per row. OUTF=0: bf16 out, 1: f32 out.
// ---------------------------------------------------------------------------
template <int OUTF>
__global__ __launch_bounds__(256)
void ln_kernel(const float* __restrict__ x, const float* __restrict__ scale,
               const float* __restrict__ bias, u16* __restrict__ hHi,
               float* __restrict__ outF) {
  const int w = threadIdx.x >> 6, lane = threadIdx.x & 63;
  const int row = blockIdx.x * 4 + w;
  const float* xr = x + (size_t)row * EMB;
  float4 vv[4];
  float s = 0.f, s2 = 0.f;
#pragma unroll
  for (int j = 0; j < 4; ++j) {
    vv[j] = *(const float4*)&xr[j * 256 + lane * 4];
    s  += vv[j].x + vv[j].y + vv[j].z + vv[j].w;
    s2 += vv[j].x * vv[j].x + vv[j].y * vv[j].y + vv[j].z * vv[j].z + vv[j].w * vv[j].w;
  }
#pragma unroll
  for (int m = 1; m < 64; m <<= 1) {
    s  += __shfl_xor(s, m);
    s2 += __shfl_xor(s2, m);
  }
  const float mu = s * (1.f / EMB);
  const float var = s2 * (1.f / EMB) - mu * mu;
  const float rs = rsqrtf(var + 1e-6f);
#pragma unroll
  for (int j = 0; j < 4; ++j) {
    int c = j * 256 + lane * 4;
    const float4 sc = *(const float4*)&scale[c];
    const float4 bi = *(const float4*)&bias[c];
    float h0 = (vv[j].x - mu) * rs * sc.x + bi.x;
    float h1 = (vv[j].y - mu) * rs * sc.y + bi.y;
    float h2 = (vv[j].z - mu) * rs * sc.z + bi.z;
    float h3 = (vv[j].w - mu) * rs * sc.w + bi.w;
    size_t o = (size_t)row * EMB + c;
    if (OUTF) {
      *(float4*)&outF[o] = make_float4(h0, h1, h2, h3);
    } else {
      u16x4 vh;
      vh[0] = f2bf(h0); vh[1] = f2bf(h1); vh[2] = f2bf(h2); vh[3] = f2bf(h3);
      *(u16x4*)&hHi[o] = vh;
    }
  }
}

// ---------------------------------------------------------------------------
// 128x128-tile bf16 GEMM (2-phase dbuf) — retained for MLP-in (EPI 0 only).
// ---------------------------------------------------------------------------
template <int EPI>
__global__ __launch_bounds__(256, 3)
void gemm1_kernel(const u16* __restrict__ A, const u16* __restrict__ B,
                  int K, int N, const float* __restrict__ bias,
                  const float* __restrict__ extra, float* __restrict__ outF,
                  u16* __restrict__ outHi) {
  const int tid = threadIdx.x;
  const int lane = tid & 63;
  const int w = tid >> 6;
  const int wm = w >> 1, wn = w & 1;
  const int bm = blockIdx.x * 128, bn = blockIdx.y * 128;
  const int l15 = lane & 15, g4 = lane >> 4;

  __shared__ u16 lds[16384];

  f32x4 acc[4][4];
#pragma unroll
  for (int i = 0; i < 4; ++i)
#pragma unroll
    for (int j = 0; j < 4; ++j) acc[i][j] = f32x4{0.f, 0.f, 0.f, 0.f};

  auto stage = [&](int buf, int k0) {
#pragma unroll
    for (int p = 0; p < 2; ++p) {
      int c = p * 256 + tid;
      int r = c >> 2;
      int gg = (c & 3) ^ ((r >> 1) & 3);
      gll16(A + (size_t)(bm + r) * K + k0 + gg * 8, &lds[buf * 8192 + c * 8]);
      gll16(B + (size_t)(bn + r) * K + k0 + gg * 8, &lds[buf * 8192 + 4096 + c * 8]);
    }
  };

  const int nk = K >> 5;
  stage(0, 0);
  for (int kt = 0; kt < nk; ++kt) {
    const int cur = kt & 1;
    __syncthreads();
    if (kt + 1 < nk) stage(cur ^ 1, (kt + 1) * 32);
    s16x8 ah[4], bh[4];
#pragma unroll
    for (int mi = 0; mi < 4; ++mi) {
      int r = wm * 64 + mi * 16 + l15;
      int chunk = (r << 2) | (g4 ^ ((r >> 1) & 3));
      ah[mi] = *(const s16x8*)&lds[cur * 8192 + chunk * 8];
    }
#pragma unroll
    for (int ni = 0; ni < 4; ++ni) {
      int r = wn * 64 + ni * 16 + l15;
      int chunk = (r << 2) | (g4 ^ ((r >> 1) & 3));
      bh[ni] = *(const s16x8*)&lds[cur * 8192 + 4096 + chunk * 8];
    }
#pragma unroll
    for (int mi = 0; mi < 4; ++mi)
#pragma unroll
      for (int ni = 0; ni < 4; ++ni)
        acc[mi][ni] = MFMA_16x16x32_BF16(ah[mi], bh[ni], acc[mi][ni], 0, 0, 0);
  }
#pragma unroll
  for (int mi = 0; mi < 4; ++mi) {
#pragma unroll
    for (int ni = 0; ni < 4; ++ni) {
      int gc = bn + wn * 64 + ni * 16 + l15;
      float bv = (EPI == 0 || EPI == 1 || EPI == 2) ? bias[gc] : 0.f;
#pragma unroll
      for (int r_ = 0; r_ < 4; ++r_) {
        int gr = bm + wm * 64 + mi * 16 + g4 * 4 + r_;
        float v = acc[mi][ni][r_] + bv;
        size_t o = (size_t)gr * N + gc;
        if (EPI == 0) {
          outF[o] = v + extra[(size_t)(gr & (SEQ - 1)) * EMB + gc];
        } else if (EPI == 1) {
          outHi[o] = f2bf(v);
        } else if (EPI == 2 || EPI == 4) {
          outF[o] = v + extra[o];
        } else {
          float t3 = v + 0.044715f * v * v * v;
          float gl = 0.5f * v * (1.f + tanhf(0.7978845608028654f * t3));
          outHi[o] = f2bf(gl);
        }
      }
    }
  }
}

// ---------------------------------------------------------------------------
// 256x256-tile bf16 GEMM, 8 waves (2M x 4N), BK=32, double-buffered 64 KiB LDS.
// 2-phase: issue next-tile stage at loop top, ds_read+MFMA current tile, one
// __syncthreads per K-step. setprio(1) around MFMA clusters.
// Swizzle: granule slot s = g4 ^ ((r>>1)&3)  -> 8 distinct bank-starts per
// 8 rows = 2-way aliasing only (free, m136); same involution on stage source
// and ds_read (rule #21). All addressing hoisted out of the K-loop.
// EPI: 1 = +bias -> bf16 (QKV); 2 = +bias +res -> f32 (proj);
//      3 = gelu -> bf16 (fc1); 4 = +res -> f32 (fc2 accumulate).
// Requires M%256==0, N%256==0, K%32==0.
// ---------------------------------------------------------------------------
template <int EPI>
__global__ __launch_bounds__(512, 2)
void gemm8_kernel(const u16* __restrict__ A, const u16* __restrict__ B,
                  int K, int N, const float* __restrict__ bias,
                  const float* __restrict__ extra, float* __restrict__ outF,
                  u16* __restrict__ outHi) {
  const int tid = threadIdx.x;              // 0..511
  const int lane = tid & 63, w = tid >> 6;  // 8 waves
  const int wm = w >> 2, wn = w & 3;        // 2 x 4
  const int bm = blockIdx.x * 256, bn = blockIdx.y * 256;
  const int l15 = lane & 15, g4 = lane >> 4;

  // buf c: A-tile [256][32] @ c*16384 u16, B-tile @ c*16384+8192. Total 64 KiB.
  __shared__ u16 lds8[32768];

  f32x4 acc[8][4];
#pragma unroll
  for (int i = 0; i < 8; ++i)
#pragma unroll
    for (int j = 0; j < 4; ++j) acc[i][j] = f32x4{0.f, 0.f, 0.f, 0.f};

  // ---- staging setup (hoisted): thread covers chunks c0=tid, c1=tid+512.
  // chunk c holds (row r=c>>2, granule slot c&3); source granule is
  // (c&3) ^ ((r>>1)&3). LDS dest is linear (wave-uniform + lane*16B).
  const int c0 = tid, c1 = tid + 512;
  const int r0 = c0 >> 2, r1 = c1 >> 2;
  const int sg0 = (c0 & 3) ^ ((r0 >> 1) & 3);
  const int sg1 = (c1 & 3) ^ ((r1 >> 1) & 3);
  const u16* pA0 = A + (size_t)(bm + r0) * K + sg0 * 8;
  const u16* pA1 = A + (size_t)(bm + r1) * K + sg1 * 8;
  const u16* pB0 = B + (size_t)(bn + r0) * K + sg0 * 8;
  const u16* pB1 = B + (size_t)(bn + r1) * K + sg1 * 8;
  u16* dA0 = &lds8[c0 * 8];
  u16* dA1 = &lds8[c1 * 8];
  u16* dB0 = &lds8[8192 + c0 * 8];
  u16* dB1 = &lds8[8192 + c1 * 8];

  // ---- ds_read offsets (u16 index), loop-invariant
  int aIdx[8], bIdx[4];
#pragma unroll
  for (int mi = 0; mi < 8; ++mi) {
    int r = wm * 128 + mi * 16 + l15;
    aIdx[mi] = ((r << 2) | (g4 ^ ((r >> 1) & 3))) * 8;
  }
#pragma unroll
  for (int ni = 0; ni < 4; ++ni) {
    int r = wn * 64 + ni * 16 + l15;
    bIdx[ni] = (((r << 2) | (g4 ^ ((r >> 1) & 3))) * 8) + 8192;
  }

  const int NK = K >> 5;
  // prologue: stage buf0 @ k=0
  gll16(pA0, dA0); gll16(pA1, dA1);
  gll16(pB0, dB0); gll16(pB1, dB1);
  pA0 += 32; pA1 += 32; pB0 += 32; pB1 += 32;
  __syncthreads();
  for (int kt = 0; kt < NK; ++kt) {
    const int ab = (kt & 1) * 16384;
    const int nb = ((kt & 1) ^ 1) * 16384;
    if (kt + 1 < NK) {                 // issue next-tile loads first
      gll16(pA0, dA0 + nb); gll16(pA1, dA1 + nb);
      gll16(pB0, dB0 + nb); gll16(pB1, dB1 + nb);
      pA0 += 32; pA1 += 32; pB0 += 32; pB1 += 32;
    }
    s16x8 Bf[4], Af[4];
#pragma unroll
    for (int ni = 0; ni < 4; ++ni)
      Bf[ni] = *(const s16x8*)&lds8[ab + bIdx[ni]];
#pragma unroll
    for (int mi = 0; mi < 4; ++mi)
      Af[mi] = *(const s16x8*)&lds8[ab + aIdx[mi]];
    __builtin_amdgcn_s_setprio(1);
#pragma unroll
    for (int mi = 0; mi < 4; ++mi)
#pragma unroll
      for (int ni = 0; ni < 4; ++ni)
        acc[mi][ni] = MFMA_16x16x32_BF16(Af[mi], Bf[ni], acc[mi][ni], 0, 0, 0);
    __builtin_amdgcn_s_setprio(0);
#pragma unroll
    for (int mi = 0; mi < 4; ++mi)
      Af[mi] = *(const s16x8*)&lds8[ab + aIdx[4 + mi]];
    __builtin_amdgcn_s_setprio(1);
#pragma unroll
    for (int mi = 0; mi < 4; ++mi)
#pragma unroll
      for (int ni = 0; ni < 4; ++ni)
        acc[4 + mi][ni] = MFMA_16x16x32_BF16(Af[mi], Bf[ni], acc[4 + mi][ni], 0, 0, 0);
    __builtin_amdgcn_s_setprio(0);
    __syncthreads();                   // one barrier per K-step
  }
  // ---- epilogue: C/D layout row=(lane>>4)*4+reg, col=lane&15 ----
#pragma unroll
  for (int fm = 0; fm < 8; ++fm) {
#pragma unroll
    for (int ni = 0; ni < 4; ++ni) {
      int gc = bn + wn * 64 + ni * 16 + l15;
      float bv = (EPI == 1 || EPI == 2) ? bias[gc] : 0.f;
#pragma unroll
      for (int r_ = 0; r_ < 4; ++r_) {
        int gr = bm + wm * 128 + fm * 16 + g4 * 4 + r_;
        float v = acc[fm][ni][r_] + bv;
        size_t o = (size_t)gr * N + gc;
        if (EPI == 1) {
          outHi[o] = f2bf(v);
        } else if (EPI == 2 || EPI == 4) {
          outF[o] = v + extra[o];
        } else {  // EPI == 3: tanh-approx GELU -> bf16
          float t3 = v + 0.044715f * v * v * v;
          float gl = 0.5f * v * (1.f + tanhf(0.7978845608028654f * t3));
          outHi[o] = f2bf(gl);
        }
      }
    }
  }
}

// ---------------------------------------------------------------------------
// Flash attention fwd, one CH-token chunk (CB batches). grid (SEQ/64, HEADS, CB),
// 256 thr = 4 waves, each wave owns 16 q-rows. qkv: bf16 [CH][3072] (q|k|v).
// ---------------------------------------------------------------------------
__global__ __launch_bounds__(256, 2)
void attn_kernel(const u16* __restrict__ qkv, u16* __restrict__ oHi) {
  const int qb = blockIdx.x, h = blockIdx.y, b = blockIdx.z;
  const int tid = threadIdx.x, lane = tid & 63, w = tid >> 6;
  const int l15 = lane & 15, g4 = lane >> 4;

  __shared__ u16 smem[2048 + 2560 + 2048];
  u16* Klds = smem;
  u16* VT   = smem + 2048;
  u16* Pw   = smem + 2048 + 2560 + w * 512;

  const int q0 = qb * 64 + w * 16;
  const size_t base = (size_t)b * SEQ * H3 + (size_t)h * 64;

  s16x8 qf0, qf1;
  {
    const u16* qp = qkv + base + (size_t)(q0 + l15) * H3 + g4 * 8;
    qf0 = *(const s16x8*)qp;
    qf1 = *(const s16x8*)(qp + 32);
  }

  f32x4 of[4];
#pragma unroll
  for (int n = 0; n < 4; ++n) of[n] = f32x4{0.f, 0.f, 0.f, 0.f};
  float mrow[4] = {-1e30f, -1e30f, -1e30f, -1e30f};
  float lrow[4] = {0.f, 0.f, 0.f, 0.f};

  for (int kt = 0; kt < SEQ; kt += 32) {
    {
      int r = tid >> 3;
      int jj = (tid & 7) ^ (r & 7);
      gll16(qkv + base + (size_t)(kt + r) * H3 + EMB + jj * 8, &Klds[tid * 8]);
    }
    {
      int key = tid >> 3, j = tid & 7;
      s16x8 v = *(const s16x8*)(qkv + base + (size_t)(kt + key) * H3 + 2 * EMB + j * 8);
#pragma unroll
      for (int i = 0; i < 8; ++i) VT[(j * 8 + i) * 40 + key] = (u16)v[i];
    }
    __syncthreads();
    const int key0 = l15, key1 = 16 + l15;
    s16x8 kf00 = *(const s16x8*)&Klds[key0 * 64 + (((0 + g4) ^ (key0 & 7)) * 8)];
    s16x8 kf01 = *(const s16x8*)&Klds[key0 * 64 + (((4 + g4) ^ (key0 & 7)) * 8)];
    s16x8 kf10 = *(const s16x8*)&Klds[key1 * 64 + (((0 + g4) ^ (key1 & 7)) * 8)];
    s16x8 kf11 = *(const s16x8*)&Klds[key1 * 64 + (((4 + g4) ^ (key1 & 7)) * 8)];
    f32x4 z = f32x4{0.f, 0.f, 0.f, 0.f};
    f32x4 s0 = MFMA_16x16x32_BF16(qf0, kf00, z, 0, 0, 0);
    s0 = MFMA_16x16x32_BF16(qf1, kf01, s0, 0, 0, 0);
    f32x4 s1 = MFMA_16x16x32_BF16(qf0, kf10, z, 0, 0, 0);
    s1 = MFMA_16x16x32_BF16(qf1, kf11, s1, 0, 0, 0);
#pragma unroll
    for (int r_ = 0; r_ < 4; ++r_) {
      float mx = fmaxf(s0[r_], s1[r_]);
      mx = fmaxf(mx, __shfl_xor(mx, 1));
      mx = fmaxf(mx, __shfl_xor(mx, 2));
      mx = fmaxf(mx, __shfl_xor(mx, 4));
      mx = fmaxf(mx, __shfl_xor(mx, 8));
      float mnew = fmaxf(mrow[r_], mx);
      float alpha = __expf((mrow[r_] - mnew) * 0.125f);
      mrow[r_] = mnew;
      float p0 = __expf((s0[r_] - mnew) * 0.125f);
      float p1 = __expf((s1[r_] - mnew) * 0.125f);
      float ts = p0 + p1;
      ts += __shfl_xor(ts, 1);
      ts += __shfl_xor(ts, 2);
      ts += __shfl_xor(ts, 4);
      ts += __shfl_xor(ts, 8);
      lrow[r_] = lrow[r_] * alpha + ts;
      of[0][r_] *= alpha; of[1][r_] *= alpha;
      of[2][r_] *= alpha; of[3][r_] *= alpha;
      int row = g4 * 4 + r_;
      int sw = (row >> 1) & 3;
      int c0 = (l15 >> 3) ^ sw;
      int c1 = (2 + (l15 >> 3)) ^ sw;
      Pw[(row * 4 + c0) * 8 + (l15 & 7)] = f2bf(p0);
      Pw[(row * 4 + c1) * 8 + (l15 & 7)] = f2bf(p1);
    }
    {
      int pchunk = (l15 << 2) | (g4 ^ ((l15 >> 1) & 3));
      s16x8 pf = *(const s16x8*)&Pw[pchunk * 8];
#pragma unroll
      for (int n = 0; n < 4; ++n) {
        s16x8 vf = *(const s16x8*)&VT[(n * 16 + l15) * 40 + g4 * 8];
        of[n] = MFMA_16x16x32_BF16(pf, vf, of[n], 0, 0, 0);
      }
    }
    __syncthreads();
  }
#pragma unroll
  for (int r_ = 0; r_ < 4; ++r_) {
    float inv = 1.f / lrow[r_];
    int qrow = q0 + g4 * 4 + r_;
    size_t ob = (size_t)(b * SEQ + qrow) * EMB + h * 64;
#pragma unroll
    for (int n = 0; n < 4; ++n)
      oHi[ob + n * 16 + l15] = f2bf(of[n][r_] * inv);
  }
}

// ---------------------------------------------------------------------------
extern "C" void kernel_launch(void* const* d_in, const int* in_sizes, int n_in,
                              void* d_out, int out_size, void* d_ws, size_t ws_size,
                              hipStream_t stream) {
  const float* image1     = (const float*)d_in[0];
  const float* image2     = (const float*)d_in[1];
  const float* text_feat  = (const float*)d_in[2];
  const float* mlp_kernel = (const float*)d_in[3];
  const float* mlp_bias   = (const float*)d_in[4];
  const float* ln1_scale  = (const float*)d_in[5];
  const float* ln1_bias   = (const float*)d_in[6];
  const float* qkv_kernel = (const float*)d_in[7];
  const float* qkv_bias   = (const float*)d_in[8];
  const float* proj_kernel= (const float*)d_in[9];
  const float* proj_bias  = (const float*)d_in[10];
  const float* ln2_scale  = (const float*)d_in[11];
  const float* ln2_bias   = (const float*)d_in[12];
  const float* fc1_kernel = (const float*)d_in[13];
  const float* fc2_kernel = (const float*)d_in[14];
  const float* lnf_scale  = (const float*)d_in[15];
  const float* lnf_bias   = (const float*)d_in[16];

  // ---- workspace layout (bytes), ~178 MiB total (< proven 194 MiB)
  size_t off = 0;
  auto take = [&](size_t bytes) { size_t o = off; off += (bytes + 255) & ~(size_t)255; return o; };
  char* ws = (char*)d_ws;
  const size_t oX    = take((size_t)TOKENS * EMB * 4);            // 64 MiB residual f32
  const size_t oPos  = take((size_t)SEQ * EMB * 4);               //  2 MiB
  const size_t oSh   = take((size_t)TOKENS * EMB * 2);            // 32 MiB: attn-out | hFull (MLP)
  const size_t oBig  = take((size_t)CH * H3 * 2 + (size_t)CH * EMB * 2); // 64 MiB: qkv(48)+hChunk(16) | fc1half(64) | feats(24)
  const size_t oWbuf = take((size_t)16 * 1024 * 1024);            // 16 MiB weight slots
  if (off > ws_size) {  // diagnostic: absmax ~1e6 next round => ws too small
    fill_kernel<<<(out_size + 255) / 256, 256, 0, stream>>>((float*)d_out, out_size);
    return;
  }

  float* x   = (float*)(ws + oX);
  float* pos = (float*)(ws + oPos);
  u16* shrd  = (u16*)(ws + oSh);
  u16* oA    = shrd;                            // attention output (full), attn phase
  u16* hFull = shrd;                            // LN2 output (full), MLP phase
  u16* big   = (u16*)(ws + oBig);
  u16* hC    = big + (size_t)CH * H3;           // per-chunk LN1 out, tail 16 MiB of big
  u16* wbuf  = (u16*)(ws + oWbuf);
  u16* wq  = wbuf;                              // 6 MiB [3072][1024]
  u16* wp  = wbuf + (size_t)3 * 1024 * 1024;    // 2 MiB [1024][1024]
  u16* wf1 = wbuf;                              // 8 MiB [4096][1024]
  u16* wf2 = wbuf + (size_t)4 * 1024 * 1024;    // 4 MiB [1024][2048]
  u16* w1t = wbuf;                              // 3 MiB [1024][1536]

  pos_kernel<<<SEQ, 256, 0, stream>>>(pos);

  // ---- MLP-in: x = concat(feats) @ W1 + b + pos (128^2 kernel, chunked)
  wtrans_kernel<<<dim3(EMB / 64, K1 / 64), 256, 0, stream>>>(mlp_kernel, w1t, K1, EMB);
  for (int c = 0; c < NCH; ++c) {
    const size_t fo = (size_t)c * CH * 512;
    concat_kernel<<<CH * K1 / 1024, 256, 0, stream>>>(image1 + fo, image2 + fo, text_feat + fo, big);
    gemm1_kernel<0><<<dim3(CH / 128, EMB / 128), 256, 0, stream>>>(
        big, w1t, K1, EMB, mlp_bias, pos, x + (size_t)c * CH * EMB, nullptr);
  }

  for (int i = 0; i < DEPTH; ++i) {
    // ---- attention: qkvT -> wq, projT -> wp
    wtrans_kernel<<<dim3(H3 / 64, EMB / 64), 256, 0, stream>>>(
        qkv_kernel + (size_t)i * EMB * H3, wq, EMB, H3);
    wtrans_kernel<<<dim3(EMB / 64, EMB / 64), 256, 0, stream>>>(
        proj_kernel + (size_t)i * EMB * EMB, wp, EMB, EMB);
    for (int c = 0; c < NCH; ++c) {
      float* xc = x + (size_t)c * CH * EMB;
      ln_kernel<0><<<CH / 4, 256, 0, stream>>>(xc, ln1_scale + i * EMB, ln1_bias + i * EMB,
                                               hC, nullptr);
      gemm8_kernel<1><<<dim3(CH / 256, H3 / 256), 512, 0, stream>>>(
          hC, wq, EMB, H3, qkv_bias + i * H3, nullptr, nullptr, big);
      attn_kernel<<<dim3(SEQ / 64, HEADS, CB), 256, 0, stream>>>(big, oA + (size_t)c * CH * EMB);
    }
    gemm8_kernel<2><<<dim3(TOKENS / 256, EMB / 256), 512, 0, stream>>>(
        oA, wp, EMB, EMB, proj_bias + i * EMB, x, x, nullptr);
    // ---- MLP: hFull = LN2(x) ONCE (before any fc2 accumulate touches x)
    ln_kernel<0><<<TOKENS / 4, 256, 0, stream>>>(x, ln2_scale + i * EMB, ln2_bias + i * EMB,
                                                 hFull, nullptr);
    wtrans_kernel<<<dim3(MLPD / 64, EMB / 64), 256, 0, stream>>>(
        fc1_kernel + (size_t)i * EMB * MLPD, wf1, EMB, MLPD);
    for (int nh = 0; nh < 2; ++nh) {
      wtrans_kernel<<<dim3(EMB / 64, 2048 / 64), 256, 0, stream>>>(
          fc2_kernel + (size_t)i * MLPD * EMB + (size_t)nh * 2048 * EMB, wf2, 2048, EMB);
      gemm8_kernel<3><<<dim3(TOKENS / 256, 2048 / 256), 512, 0, stream>>>(
          hFull, wf1 + (size_t)nh * 2048 * 1024, EMB, 2048, nullptr, nullptr, nullptr, big);
      gemm8_kernel<4><<<dim3(TOKENS / 256, EMB / 256), 512, 0, stream>>>(
          big, wf2, 2048, EMB, nullptr, x, x, nullptr);
    }
  }
  ln_kernel<1><<<TOKENS / 4, 256, 0, stream>>>(x, lnf_scale, lnf_bias,
                                               nullptr, (float*)d_out);
}